// Round 1
// baseline (11877.332 us; speedup 1.0000x reference)
//
#include <hip/hip_runtime.h>
#include <hip/hip_bf16.h>
#include <math.h>

// ---------------- problem dims ----------------
#define TT   128
#define BB   128
#define TB   (TT*BB)         // 16384
#define CC   16
#define HH   16
#define WW   16
#define CHW  4096
#define HID  512
#define G4   2048            // 4*HID
#define ZD   8
#define AD   7
#define FE   128
#define LOFK 520             // HID + ZD

#define IMG_ROW 20           // padded conv row: x in [-2,17], 16B-aligned

// ================= fused conv1(5x5)+conv2(3x3)+conv3(3x3), leaky =================
template<int K>
__device__ __forceinline__ void conv_stage(const float* __restrict__ sin,
                                           float* __restrict__ sout,
                                           const float* __restrict__ sw,
                                           float bias, int co, int y) {
  float acc[16];
#pragma unroll
  for (int i = 0; i < 16; ++i) acc[i] = bias;
#pragma unroll
  for (int ci = 0; ci < 16; ++ci) {
#pragma unroll
    for (int ky = 0; ky < K; ++ky) {
      const int iy = y + ky - K / 2;
      if (iy < 0 || iy > 15) continue;
      const float* rp = &sin[(ci * 16 + iy) * IMG_ROW];
      float row[20];
#pragma unroll
      for (int q = 0; q < 5; ++q) *(float4*)&row[q * 4] = *(const float4*)&rp[q * 4];
      const float* wp = &sw[((co * 16 + ci) * K + ky) * K];
#pragma unroll
      for (int kx = 0; kx < K; ++kx) {
        const float wv = wp[kx];
        const int base = kx + (K == 5 ? 0 : 1);  // padded-coord offset
#pragma unroll
        for (int xx = 0; xx < 16; ++xx) acc[xx] += wv * row[xx + base];
      }
    }
  }
  float* orow = &sout[(co * 16 + y) * IMG_ROW];
  orow[0] = 0.f; orow[1] = 0.f; orow[18] = 0.f; orow[19] = 0.f;
#pragma unroll
  for (int xx = 0; xx < 16; ++xx) {
    float v = acc[xx];
    orow[2 + xx] = v > 0.f ? v : 0.01f * v;
  }
}

__global__ __launch_bounds__(256) void conv_fused_kernel(
    const float* __restrict__ x,
    const float* __restrict__ w1, const float* __restrict__ b1,
    const float* __restrict__ w2, const float* __restrict__ b2,
    const float* __restrict__ w3, const float* __restrict__ b3,
    float* __restrict__ out) {
  __shared__ float imgA[256 * IMG_ROW];
  __shared__ float imgB[256 * IMG_ROW];
  __shared__ float ws[16 * 16 * 5 * 5];
  const int img = blockIdx.x;
  const int tid = threadIdx.x;
  const int co = tid >> 4, y = tid & 15;

  // zero halos of imgA (one row per thread)
  {
    float* r = &imgA[tid * IMG_ROW];
    r[0] = 0.f; r[1] = 0.f; r[18] = 0.f; r[19] = 0.f;
  }
  const float* src = x + (size_t)img * CHW;
  for (int i = tid; i < CHW; i += 256)
    imgA[(i >> 4) * IMG_ROW + 2 + (i & 15)] = src[i];
  for (int i = tid; i < 6400; i += 256) ws[i] = w1[i];
  __syncthreads();
  conv_stage<5>(imgA, imgB, ws, b1[co], co, y);
  __syncthreads();
  for (int i = tid; i < 2304; i += 256) ws[i] = w2[i];
  __syncthreads();
  conv_stage<3>(imgB, imgA, ws, b2[co], co, y);
  __syncthreads();
  for (int i = tid; i < 2304; i += 256) ws[i] = w3[i];
  __syncthreads();
  conv_stage<3>(imgA, imgB, ws, b3[co], co, y);
  __syncthreads();
  float* dst = out + (size_t)img * CHW;
  for (int i = tid; i < CHW; i += 256)
    dst[i] = imgB[(i >> 4) * IMG_ROW + 2 + (i & 15)];
}

// ================= tiled fp32 GEMM: out[N,M] = act(A[N,K] @ W[M,ldw]^T + bias) =================
template<bool LEAKY>
__global__ __launch_bounds__(256) void fc_kernel(
    const float* __restrict__ A, const float* __restrict__ W,
    const float* __restrict__ bias, float* __restrict__ out,
    int K, int ldw, int M) {
  __shared__ float As[32][68];
  __shared__ float Ws[32][68];
  const int tid = threadIdx.x;
  const int rb = blockIdx.y << 6;
  const int cb = blockIdx.x << 6;
  const int ti = tid >> 4, tj = tid & 15;
  float acc[4][4] = {{0.f}};
  const float* Ap = A + (size_t)rb * K;
  const float* Wp = W + (size_t)cb * ldw;

  for (int k0 = 0; k0 < K; k0 += 32) {
#pragma unroll
    for (int l = 0; l < 2; ++l) {
      const int idx = tid + (l << 8);   // 0..511 float4 slots
      const int row = idx >> 3, kq = idx & 7;
      float4 av = *(const float4*)(Ap + (size_t)row * K + k0 + kq * 4);
      As[kq * 4 + 0][row] = av.x; As[kq * 4 + 1][row] = av.y;
      As[kq * 4 + 2][row] = av.z; As[kq * 4 + 3][row] = av.w;
      float4 wv = *(const float4*)(Wp + (size_t)row * ldw + k0 + kq * 4);
      Ws[kq * 4 + 0][row] = wv.x; Ws[kq * 4 + 1][row] = wv.y;
      Ws[kq * 4 + 2][row] = wv.z; Ws[kq * 4 + 3][row] = wv.w;
    }
    __syncthreads();
#pragma unroll
    for (int kk = 0; kk < 32; ++kk) {
      float4 a4 = *(const float4*)&As[kk][ti << 2];
      float4 w4 = *(const float4*)&Ws[kk][tj << 2];
      acc[0][0] += a4.x * w4.x; acc[0][1] += a4.x * w4.y;
      acc[0][2] += a4.x * w4.z; acc[0][3] += a4.x * w4.w;
      acc[1][0] += a4.y * w4.x; acc[1][1] += a4.y * w4.y;
      acc[1][2] += a4.y * w4.z; acc[1][3] += a4.y * w4.w;
      acc[2][0] += a4.z * w4.x; acc[2][1] += a4.z * w4.y;
      acc[2][2] += a4.z * w4.z; acc[2][3] += a4.z * w4.w;
      acc[3][0] += a4.w * w4.x; acc[3][1] += a4.w * w4.y;
      acc[3][2] += a4.w * w4.z; acc[3][3] += a4.w * w4.w;
    }
    __syncthreads();
  }
  float4 b4 = make_float4(0.f, 0.f, 0.f, 0.f);
  if (bias) b4 = *(const float4*)(bias + cb + (tj << 2));
#pragma unroll
  for (int r = 0; r < 4; ++r) {
    const size_t orow = rb + (ti << 2) + r;
    float4 v;
    v.x = acc[r][0] + b4.x; v.y = acc[r][1] + b4.y;
    v.z = acc[r][2] + b4.z; v.w = acc[r][3] + b4.w;
    if (LEAKY) {
      v.x = v.x > 0.f ? v.x : 0.01f * v.x;
      v.y = v.y > 0.f ? v.y : 0.01f * v.y;
      v.z = v.z > 0.f ? v.z : 0.01f * v.z;
      v.w = v.w > 0.f ? v.w : 0.01f * v.w;
    }
    *(float4*)(out + orow * M + cb + (tj << 2)) = v;
  }
}

// ================= tiny: combined gate bias =================
__global__ void bias_add_kernel(const float* __restrict__ a, const float* __restrict__ b,
                                float* __restrict__ o, int n) {
  int i = blockIdx.x * 256 + threadIdx.x;
  if (i < n) o[i] = a[i] + b[i];
}

// ================= LSTM step: gates_hh GEMM + pointwise =================
// grid (32 j-tiles of 16, 8 batch-tiles of 16), 256 threads: thread=(b_loc,j_loc) owns (b,j,4 gates)
__global__ __launch_bounds__(256) void lstm_step_kernel(
    const float* __restrict__ gates_ih,  // + t*B*2048
    const int* __restrict__ done_t,      // + t*B
    const float* __restrict__ w_hh,      // [2048][512]
    const float* __restrict__ h_read,    // [128][512]
    float* __restrict__ h_write,         // [128][512]
    float* __restrict__ c_state,         // [128][512]
    float* __restrict__ outs_t)          // + t*B*512
{
  __shared__ float hm[16][512];
  const int tid = threadIdx.x;
  const int bt = blockIdx.y << 4;
  const int j0 = blockIdx.x << 4;
  const int b_loc = tid >> 4, j_loc = tid & 15;

  // stage (h * m) for this batch tile
#pragma unroll
  for (int l = 0; l < 8; ++l) {
    const int idx = tid + (l << 8);      // 0..2047 float4 slots
    const int bb = idx >> 7;
    const int kk = (idx & 127) << 2;
    const float m = 1.f - (float)done_t[bt + bb];
    float4 h4 = *(const float4*)(h_read + (size_t)(bt + bb) * HID + kk);
    h4.x *= m; h4.y *= m; h4.z *= m; h4.w *= m;
    *(float4*)&hm[bb][kk] = h4;
  }
  __syncthreads();

  const int b = bt + b_loc;
  const int j = j0 + j_loc;
  float acc0 = 0.f, acc1 = 0.f, acc2 = 0.f, acc3 = 0.f;
  const float* w0 = w_hh + (size_t)(0 * HID + j) * HID;
  const float* w1 = w_hh + (size_t)(1 * HID + j) * HID;
  const float* w2 = w_hh + (size_t)(2 * HID + j) * HID;
  const float* w3 = w_hh + (size_t)(3 * HID + j) * HID;
  for (int k = 0; k < HID; k += 4) {
    const float4 h4 = *(const float4*)&hm[b_loc][k];
    const float4 a4 = *(const float4*)(w0 + k);
    const float4 f4 = *(const float4*)(w1 + k);
    const float4 g4 = *(const float4*)(w2 + k);
    const float4 o4 = *(const float4*)(w3 + k);
    acc0 += h4.x * a4.x + h4.y * a4.y + h4.z * a4.z + h4.w * a4.w;
    acc1 += h4.x * f4.x + h4.y * f4.y + h4.z * f4.z + h4.w * f4.w;
    acc2 += h4.x * g4.x + h4.y * g4.y + h4.z * g4.z + h4.w * g4.w;
    acc3 += h4.x * o4.x + h4.y * o4.y + h4.z * o4.z + h4.w * o4.w;
  }
  const size_t gb = (size_t)b * G4;
  const float gi = gates_ih[gb + j]             + acc0;
  const float gf = gates_ih[gb + HID + j]       + acc1;
  const float gg = gates_ih[gb + 2 * HID + j]   + acc2;
  const float go = gates_ih[gb + 3 * HID + j]   + acc3;
  const float m  = 1.f - (float)done_t[b];
  const float c_old = c_state[(size_t)b * HID + j] * m;
  const float i_s = 1.f / (1.f + __expf(-gi));
  const float f_s = 1.f / (1.f + __expf(-gf));
  const float o_s = 1.f / (1.f + __expf(-go));
  const float g_t = tanhf(gg);
  const float c_new = f_s * c_old + i_s * g_t;
  const float h_new = o_s * tanhf(c_new);
  c_state[(size_t)b * HID + j] = c_new;
  h_write[(size_t)b * HID + j] = h_new;
  outs_t[(size_t)b * HID + j]  = h_new;
}

// ================= heads: z-onehot col + bias + leaky, actor/critic, softmax stats =================
__global__ __launch_bounds__(256) void heads_kernel(
    const float* __restrict__ raw,   // [TB][128]  (feat @ lofeat_w[:, :512]^T, no bias)
    const float* __restrict__ lw,    // lofeat_w [128][520]
    const float* __restrict__ lb,    // [128]
    const float* __restrict__ aw,    // [7][128]
    const float* __restrict__ ab,    // [7]
    const float* __restrict__ cw,    // [1][128]
    const float* __restrict__ cbias, // [1]
    const int* __restrict__ z, const int* __restrict__ action,
    float* __restrict__ out)         // [TB][10]
{
  const int lane = threadIdx.x & 63;
  const int s = blockIdx.x * 4 + (threadIdx.x >> 6);
  const int zv = z[s];
  float v0 = raw[(size_t)s * FE + lane]      + lw[(size_t)lane * LOFK + HID + zv]        + lb[lane];
  float v1 = raw[(size_t)s * FE + 64 + lane] + lw[(size_t)(64 + lane) * LOFK + HID + zv] + lb[64 + lane];
  v0 = v0 > 0.f ? v0 : 0.01f * v0;
  v1 = v1 > 0.f ? v1 : 0.01f * v1;

  float logits[AD];
#pragma unroll
  for (int j = 0; j < AD; ++j) {
    float p = aw[j * FE + lane] * v0 + aw[j * FE + 64 + lane] * v1;
#pragma unroll
    for (int o = 32; o > 0; o >>= 1) p += __shfl_down(p, o, 64);
    logits[j] = __shfl(p, 0, 64) + ab[j];
  }
  float val = cw[lane] * v0 + cw[64 + lane] * v1;
#pragma unroll
  for (int o = 32; o > 0; o >>= 1) val += __shfl_down(val, o, 64);
  val = __shfl(val, 0, 64) + cbias[0];

  float mx = logits[0];
#pragma unroll
  for (int j = 1; j < AD; ++j) mx = fmaxf(mx, logits[j]);
  float ex[AD], S = 0.f;
#pragma unroll
  for (int j = 0; j < AD; ++j) { ex[j] = __expf(logits[j] - mx); S += ex[j]; }
  const float inv = 1.f / S;
  const float lZ = __logf(S) + mx;
  float ent = 0.f;
#pragma unroll
  for (int j = 0; j < AD; ++j) ent += (ex[j] * inv) * (logits[j] - lZ);
  ent = -ent;
  const float lp_a = logits[action[s]] - lZ;

  if (lane < 10) {
    float v;
    if (lane == 0)      v = lp_a;
    else if (lane == 1) v = ent;
    else if (lane == 2) v = val;
    else                v = ex[lane - 3] * inv;
    out[(size_t)s * 10 + lane] = v;
  }
}

// ================= launch =================
extern "C" void kernel_launch(void* const* d_in, const int* in_sizes, int n_in,
                              void* d_out, int out_size, void* d_ws, size_t ws_size,
                              hipStream_t stream) {
  const float* x       = (const float*)d_in[0];
  const int*   done    = (const int*)d_in[1];
  const int*   z       = (const int*)d_in[2];
  const int*   action  = (const int*)d_in[3];
  const float* h0      = (const float*)d_in[4];
  const float* c0      = (const float*)d_in[5];
  const float* conv1_w = (const float*)d_in[6];
  const float* conv1_b = (const float*)d_in[7];
  const float* conv2_w = (const float*)d_in[8];
  const float* conv2_b = (const float*)d_in[9];
  const float* conv3_w = (const float*)d_in[10];
  const float* conv3_b = (const float*)d_in[11];
  const float* fc1_w   = (const float*)d_in[12];
  const float* fc1_b   = (const float*)d_in[13];
  const float* fc2_w   = (const float*)d_in[14];
  const float* fc2_b   = (const float*)d_in[15];
  const float* w_ih    = (const float*)d_in[16];
  const float* w_hh    = (const float*)d_in[17];
  const float* b_ih    = (const float*)d_in[18];
  const float* b_hh    = (const float*)d_in[19];
  const float* lofeat_w= (const float*)d_in[20];
  const float* lofeat_b= (const float*)d_in[21];
  const float* actor_w = (const float*)d_in[22];
  const float* actor_b = (const float*)d_in[23];
  const float* critic_w= (const float*)d_in[24];
  const float* critic_b= (const float*)d_in[25];
  float* out = (float*)d_out;

  // -------- workspace layout (floats) --------
  char* wsb = (char*)d_ws;
  float* conv3out = (float*)wsb;                               // 16384*4096  (268.4 MB)
  float* gates    = conv3out;                                  // overlays conv3out after fc1
  float* fc1out   = (float*)(wsb + (size_t)TB * CHW * 4);      // 16384*512
  float* fc2out   = fc1out + (size_t)TB * HID;                 // 16384*512
  float* feat     = fc2out + (size_t)TB * HID;                 // 16384*512 (LSTM outs)
  float* rawlf    = feat + (size_t)TB * HID;                   // 16384*128
  float* hbuf0    = rawlf + (size_t)TB * FE;                   // 128*512
  float* hbuf1    = hbuf0 + (size_t)BB * HID;
  float* cbuf     = hbuf1 + (size_t)BB * HID;
  float* combbias = cbuf + (size_t)BB * HID;                   // 2048

  // 1. fused convs
  conv_fused_kernel<<<TB, 256, 0, stream>>>(x, conv1_w, conv1_b, conv2_w, conv2_b,
                                            conv3_w, conv3_b, conv3out);
  // 2. fc1 (K=4096) + leaky
  fc_kernel<true><<<dim3(HID / 64, TB / 64), 256, 0, stream>>>(
      conv3out, fc1_w, fc1_b, fc1out, CHW, CHW, HID);
  // 3. fc2 (K=512) + leaky
  fc_kernel<true><<<dim3(HID / 64, TB / 64), 256, 0, stream>>>(
      fc1out, fc2_w, fc2_b, fc2out, HID, HID, HID);
  // 4. combined gate bias
  bias_add_kernel<<<(G4 + 255) / 256, 256, 0, stream>>>(b_ih, b_hh, combbias, G4);
  // 5. input-side gates for all timesteps (overlays conv3out, dead after fc1)
  fc_kernel<false><<<dim3(G4 / 64, TB / 64), 256, 0, stream>>>(
      fc2out, w_ih, combbias, gates, HID, HID, G4);
  // 6. init LSTM state
  hipMemcpyAsync(hbuf0, h0, (size_t)BB * HID * 4, hipMemcpyDeviceToDevice, stream);
  hipMemcpyAsync(cbuf, c0, (size_t)BB * HID * 4, hipMemcpyDeviceToDevice, stream);
  // 7. LSTM steps (ping-pong h)
  for (int t = 0; t < TT; ++t) {
    float* hr = (t & 1) ? hbuf1 : hbuf0;
    float* hw = (t & 1) ? hbuf0 : hbuf1;
    lstm_step_kernel<<<dim3(HID / 16, BB / 16), 256, 0, stream>>>(
        gates + (size_t)t * BB * G4, done + (size_t)t * BB, w_hh,
        hr, hw, cbuf, feat + (size_t)t * BB * HID);
  }
  // 8. lofeat GEMM (first 512 cols of lofeat_w; bias/z-col applied in heads)
  fc_kernel<false><<<dim3(FE / 64, TB / 64), 256, 0, stream>>>(
      feat, lofeat_w, nullptr, rawlf, HID, LOFK, FE);
  // 9. heads
  heads_kernel<<<TB / 4, 256, 0, stream>>>(rawlf, lofeat_w, lofeat_b, actor_w, actor_b,
                                           critic_w, critic_b, z, action, out);
}

// Round 2
// 5370.484 us; speedup vs baseline: 2.2116x; 2.2116x over previous
//
#include <hip/hip_runtime.h>
#include <hip/hip_bf16.h>
#include <math.h>

// ---------------- problem dims ----------------
#define TT   128
#define BB   128
#define TB   (TT*BB)         // 16384
#define CHW  4096
#define HID  512
#define G4   2048            // 4*HID
#define ZD   8
#define AD   7
#define FE   128
#define LOFK 520             // HID + ZD

#define IMG_ROW 20           // padded conv row

typedef __attribute__((ext_vector_type(8))) short short8;
typedef __attribute__((ext_vector_type(4))) float f32x4;

__device__ __forceinline__ unsigned short f2b(float f) {
  unsigned int u = __float_as_uint(f);
  unsigned int r = (u + 0x7FFFu + ((u >> 16) & 1u)) >> 16;
  return (unsigned short)r;
}

__device__ __forceinline__ void glds16(const void* g, void* l) {
  __builtin_amdgcn_global_load_lds((const __attribute__((address_space(1))) void*)g,
                                   (__attribute__((address_space(3))) void*)l, 16, 0, 0);
}

// ================= fused conv1(5x5)+conv2(3x3)+conv3(3x3), leaky -> bf16 out =================
template<int K>
__device__ __forceinline__ void conv_stage(const float* __restrict__ sin,
                                           float* __restrict__ sout,
                                           const float* __restrict__ sw,
                                           float bias, int co, int y) {
  float acc[16];
#pragma unroll
  for (int i = 0; i < 16; ++i) acc[i] = bias;
#pragma unroll
  for (int ci = 0; ci < 16; ++ci) {
#pragma unroll
    for (int ky = 0; ky < K; ++ky) {
      const int iy = y + ky - K / 2;
      if (iy < 0 || iy > 15) continue;
      const float* rp = &sin[(ci * 16 + iy) * IMG_ROW];
      float row[20];
#pragma unroll
      for (int q = 0; q < 5; ++q) *(float4*)&row[q * 4] = *(const float4*)&rp[q * 4];
      const float* wp = &sw[((co * 16 + ci) * K + ky) * K];
#pragma unroll
      for (int kx = 0; kx < K; ++kx) {
        const float wv = wp[kx];
        const int base = kx + (K == 5 ? 0 : 1);
#pragma unroll
        for (int xx = 0; xx < 16; ++xx) acc[xx] += wv * row[xx + base];
      }
    }
  }
  float* orow = &sout[(co * 16 + y) * IMG_ROW];
  orow[0] = 0.f; orow[1] = 0.f; orow[18] = 0.f; orow[19] = 0.f;
#pragma unroll
  for (int xx = 0; xx < 16; ++xx) {
    float v = acc[xx];
    orow[2 + xx] = v > 0.f ? v : 0.01f * v;
  }
}

__global__ __launch_bounds__(256) void conv_fused_kernel(
    const float* __restrict__ x,
    const float* __restrict__ w1, const float* __restrict__ b1,
    const float* __restrict__ w2, const float* __restrict__ b2,
    const float* __restrict__ w3, const float* __restrict__ b3,
    unsigned short* __restrict__ out) {
  __shared__ float imgA[256 * IMG_ROW];
  __shared__ float imgB[256 * IMG_ROW];
  __shared__ float ws[16 * 16 * 5 * 5];
  const int img = blockIdx.x;
  const int tid = threadIdx.x;
  const int co = tid >> 4, y = tid & 15;
  {
    float* r = &imgA[tid * IMG_ROW];
    r[0] = 0.f; r[1] = 0.f; r[18] = 0.f; r[19] = 0.f;
  }
  const float* src = x + (size_t)img * CHW;
  for (int i = tid; i < CHW; i += 256)
    imgA[(i >> 4) * IMG_ROW + 2 + (i & 15)] = src[i];
  for (int i = tid; i < 6400; i += 256) ws[i] = w1[i];
  __syncthreads();
  conv_stage<5>(imgA, imgB, ws, b1[co], co, y);
  __syncthreads();
  for (int i = tid; i < 2304; i += 256) ws[i] = w2[i];
  __syncthreads();
  conv_stage<3>(imgB, imgA, ws, b2[co], co, y);
  __syncthreads();
  for (int i = tid; i < 2304; i += 256) ws[i] = w3[i];
  __syncthreads();
  conv_stage<3>(imgA, imgB, ws, b3[co], co, y);
  __syncthreads();
  unsigned short* dst = out + (size_t)img * CHW;
  for (int i = tid; i < CHW; i += 256)
    dst[i] = f2b(imgB[(i >> 4) * IMG_ROW + 2 + (i & 15)]);
}

// ================= bf16 MFMA GEMM: out[N,M] = act(A[N,K] @ W[M,K]^T + bias) =================
// 128x128 tile, BK=32, 4 waves each computing a 64x64 quadrant as 4x4 of 16x16x32 MFMAs.
// A,W bf16 (ushort bits) row-major with ld=K. Staging via global_load_lds width=16.
template<bool LEAKY, bool OUTBF>
__global__ __launch_bounds__(256) void mfma_fc(
    const unsigned short* __restrict__ A, const unsigned short* __restrict__ W,
    const float* __restrict__ bias, void* __restrict__ outp, int K, int M) {
  __shared__ unsigned short As[128 * 32];
  __shared__ unsigned short Bs[128 * 32];
  const int tid = threadIdx.x;
  const int wv = tid >> 6, lane = tid & 63;
  const int quad = lane >> 4, l16 = lane & 15;
  const int wr = (wv >> 1) * 64, wc = (wv & 1) * 64;
  const int rb = blockIdx.y * 128, cb = blockIdx.x * 128;

  // staging slots (each = 16B = 8 bf16); slot s -> row s>>2, colq s&3
  const int s0 = tid, s1 = tid + 256;
  const int r0 = s0 >> 2, q0 = s0 & 3;
  const int r1 = s1 >> 2, q1 = s1 & 3;
  const unsigned short* A0 = A + (size_t)(rb + r0) * K + q0 * 8;
  const unsigned short* A1 = A + (size_t)(rb + r1) * K + q1 * 8;
  const unsigned short* W0 = W + (size_t)(cb + r0) * K + q0 * 8;
  const unsigned short* W1 = W + (size_t)(cb + r1) * K + q1 * 8;
  void* ldsA0 = (void*)&As[(wv * 64) * 8];
  void* ldsA1 = (void*)&As[(256 + wv * 64) * 8];
  void* ldsB0 = (void*)&Bs[(wv * 64) * 8];
  void* ldsB1 = (void*)&Bs[(256 + wv * 64) * 8];

  f32x4 acc[4][4];
#pragma unroll
  for (int i = 0; i < 4; ++i)
#pragma unroll
    for (int j = 0; j < 4; ++j)
#pragma unroll
      for (int r = 0; r < 4; ++r) acc[i][j][r] = 0.f;

  for (int k0 = 0; k0 < K; k0 += 32) {
    glds16(A0 + k0, ldsA0);
    glds16(A1 + k0, ldsA1);
    glds16(W0 + k0, ldsB0);
    glds16(W1 + k0, ldsB1);
    __syncthreads();
    short8 af[4], bf[4];
#pragma unroll
    for (int i = 0; i < 4; ++i)
      af[i] = *(const short8*)&As[(wr + i * 16 + l16) * 32 + quad * 8];
#pragma unroll
    for (int j = 0; j < 4; ++j)
      bf[j] = *(const short8*)&Bs[(wc + j * 16 + l16) * 32 + quad * 8];
#pragma unroll
    for (int i = 0; i < 4; ++i)
#pragma unroll
      for (int j = 0; j < 4; ++j)
        acc[i][j] = __builtin_amdgcn_mfma_f32_16x16x32_bf16(af[i], bf[j], acc[i][j], 0, 0, 0);
    __syncthreads();
  }

#pragma unroll
  for (int j = 0; j < 4; ++j) {
    const int col = cb + wc + j * 16 + l16;
    const float bj = bias ? bias[col] : 0.f;
#pragma unroll
    for (int i = 0; i < 4; ++i) {
#pragma unroll
      for (int r = 0; r < 4; ++r) {
        const size_t row = rb + wr + i * 16 + quad * 4 + r;
        float v = acc[i][j][r] + bj;
        if (LEAKY) v = v > 0.f ? v : 0.01f * v;
        if (OUTBF) ((unsigned short*)outp)[row * M + col] = f2b(v);
        else       ((float*)outp)[row * M + col] = v;
      }
    }
  }
}

// ================= LSTM step: MFMA gates_hh + fused cell pointwise =================
// 16 blocks; block j0=blockIdx.x*32 computes gates for cols jj in [j0,j0+32) x 4 gates
// as one 128(batch) x 128(col) MFMA tile; col c -> gate g=c>>5, w_hh row g*512+j0+(c&31).
// h enters pre-masked bf16; c enters pre-masked fp32. Epilogue applies NEXT step's mask.
__global__ __launch_bounds__(256) void lstm_step(
    const float* __restrict__ gih,        // gates_ih + t*B*2048
    const unsigned short* __restrict__ whh,  // bf16 [2048][512]
    const unsigned short* __restrict__ hm,   // bf16 [128][512] pre-masked
    float* __restrict__ cm,               // fp32 [128][512] pre-masked, in-place
    const int* __restrict__ done_next,    // [128]
    unsigned short* __restrict__ hm_out,  // bf16 pre-masked for next step
    unsigned short* __restrict__ feat_t)  // bf16 [128][512], unmasked h
{
  __shared__ unsigned short As[128 * 32];
  __shared__ unsigned short Bs[128 * 32];
  __shared__ float gb[128][132];
  const int tid = threadIdx.x;
  const int wv = tid >> 6, lane = tid & 63;
  const int quad = lane >> 4, l16 = lane & 15;
  const int wr = (wv >> 1) * 64, wc = (wv & 1) * 64;
  const int j0 = blockIdx.x * 32;

  const int s0 = tid, s1 = tid + 256;
  const int r0 = s0 >> 2, q0 = s0 & 3;
  const int r1 = s1 >> 2, q1 = s1 & 3;
  // B rows: col c -> w_hh row (c>>5)*512 + j0 + (c&31)
  const int wrow0 = (r0 >> 5) * HID + j0 + (r0 & 31);
  const int wrow1 = (r1 >> 5) * HID + j0 + (r1 & 31);
  const unsigned short* A0 = hm + (size_t)r0 * HID + q0 * 8;
  const unsigned short* A1 = hm + (size_t)r1 * HID + q1 * 8;
  const unsigned short* W0 = whh + (size_t)wrow0 * HID + q0 * 8;
  const unsigned short* W1 = whh + (size_t)wrow1 * HID + q1 * 8;
  void* ldsA0 = (void*)&As[(wv * 64) * 8];
  void* ldsA1 = (void*)&As[(256 + wv * 64) * 8];
  void* ldsB0 = (void*)&Bs[(wv * 64) * 8];
  void* ldsB1 = (void*)&Bs[(256 + wv * 64) * 8];

  f32x4 acc[4][4];
#pragma unroll
  for (int i = 0; i < 4; ++i)
#pragma unroll
    for (int j = 0; j < 4; ++j)
#pragma unroll
      for (int r = 0; r < 4; ++r) acc[i][j][r] = 0.f;

  for (int k0 = 0; k0 < HID; k0 += 32) {
    glds16(A0 + k0, ldsA0);
    glds16(A1 + k0, ldsA1);
    glds16(W0 + k0, ldsB0);
    glds16(W1 + k0, ldsB1);
    __syncthreads();
    short8 af[4], bf[4];
#pragma unroll
    for (int i = 0; i < 4; ++i)
      af[i] = *(const short8*)&As[(wr + i * 16 + l16) * 32 + quad * 8];
#pragma unroll
    for (int j = 0; j < 4; ++j)
      bf[j] = *(const short8*)&Bs[(wc + j * 16 + l16) * 32 + quad * 8];
#pragma unroll
    for (int i = 0; i < 4; ++i)
#pragma unroll
      for (int j = 0; j < 4; ++j)
        acc[i][j] = __builtin_amdgcn_mfma_f32_16x16x32_bf16(af[i], bf[j], acc[i][j], 0, 0, 0);
    __syncthreads();
  }

  // write gates_hh tile to LDS for cross-gate recombination
#pragma unroll
  for (int i = 0; i < 4; ++i)
#pragma unroll
    for (int j = 0; j < 4; ++j)
#pragma unroll
      for (int r = 0; r < 4; ++r)
        gb[wr + i * 16 + quad * 4 + r][wc + j * 16 + l16] = acc[i][j][r];
  __syncthreads();

  // pointwise: 128 batch x 32 cols = 4096 cells, 16 per thread
#pragma unroll
  for (int l = 0; l < 16; ++l) {
    const int e = tid + l * 256;
    const int b = e >> 5, jl = e & 31;
    const int j = j0 + jl;
    const size_t gbase = (size_t)b * G4;
    const float gi = gb[b][jl]      + gih[gbase + j];
    const float gf = gb[b][32 + jl] + gih[gbase + HID + j];
    const float gg = gb[b][64 + jl] + gih[gbase + 2 * HID + j];
    const float go = gb[b][96 + jl] + gih[gbase + 3 * HID + j];
    const float c_old = cm[(size_t)b * HID + j];
    const float i_s = 1.f / (1.f + __expf(-gi));
    const float f_s = 1.f / (1.f + __expf(-gf));
    const float o_s = 1.f / (1.f + __expf(-go));
    const float g_t = tanhf(gg);
    const float c_new = f_s * c_old + i_s * g_t;
    const float h_new = o_s * tanhf(c_new);
    const float mn = 1.f - (float)done_next[b];
    cm[(size_t)b * HID + j]     = c_new * mn;
    hm_out[(size_t)b * HID + j] = f2b(h_new * mn);
    feat_t[(size_t)b * HID + j] = f2b(h_new);
  }
}

// ================= small prep kernels =================
__global__ void f2b_kernel(const float* __restrict__ in, unsigned short* __restrict__ out, int n) {
  int i = blockIdx.x * 256 + threadIdx.x;
  if (i < n) out[i] = f2b(in[i]);
}
__global__ void lofpack_kernel(const float* __restrict__ lw, unsigned short* __restrict__ out) {
  int i = blockIdx.x * 256 + threadIdx.x;  // 65536
  int r = i >> 9, c = i & 511;
  out[i] = f2b(lw[r * LOFK + c]);
}
__global__ void bias_add_kernel(const float* __restrict__ a, const float* __restrict__ b,
                                float* __restrict__ o, int n) {
  int i = blockIdx.x * 256 + threadIdx.x;
  if (i < n) o[i] = a[i] + b[i];
}
__global__ void lstm_init_kernel(const float* __restrict__ h0, const float* __restrict__ c0,
                                 const int* __restrict__ done0,
                                 unsigned short* __restrict__ hm, float* __restrict__ cm) {
  int i = blockIdx.x * 256 + threadIdx.x;  // 65536
  int b = i >> 9;
  float m = 1.f - (float)done0[b];
  hm[i] = f2b(h0[i] * m);
  cm[i] = c0[i] * m;
}

// ================= heads =================
__global__ __launch_bounds__(256) void heads_kernel(
    const float* __restrict__ raw, const float* __restrict__ lw, const float* __restrict__ lb,
    const float* __restrict__ aw, const float* __restrict__ ab,
    const float* __restrict__ cw, const float* __restrict__ cbias,
    const int* __restrict__ z, const int* __restrict__ action,
    float* __restrict__ out) {
  const int lane = threadIdx.x & 63;
  const int s = blockIdx.x * 4 + (threadIdx.x >> 6);
  const int zv = z[s];
  float v0 = raw[(size_t)s * FE + lane]      + lw[(size_t)lane * LOFK + HID + zv]        + lb[lane];
  float v1 = raw[(size_t)s * FE + 64 + lane] + lw[(size_t)(64 + lane) * LOFK + HID + zv] + lb[64 + lane];
  v0 = v0 > 0.f ? v0 : 0.01f * v0;
  v1 = v1 > 0.f ? v1 : 0.01f * v1;

  float logits[AD];
#pragma unroll
  for (int j = 0; j < AD; ++j) {
    float p = aw[j * FE + lane] * v0 + aw[j * FE + 64 + lane] * v1;
#pragma unroll
    for (int o = 32; o > 0; o >>= 1) p += __shfl_down(p, o, 64);
    logits[j] = __shfl(p, 0, 64) + ab[j];
  }
  float val = cw[lane] * v0 + cw[64 + lane] * v1;
#pragma unroll
  for (int o = 32; o > 0; o >>= 1) val += __shfl_down(val, o, 64);
  val = __shfl(val, 0, 64) + cbias[0];

  float mx = logits[0];
#pragma unroll
  for (int j = 1; j < AD; ++j) mx = fmaxf(mx, logits[j]);
  float ex[AD], S = 0.f;
#pragma unroll
  for (int j = 0; j < AD; ++j) { ex[j] = __expf(logits[j] - mx); S += ex[j]; }
  const float inv = 1.f / S;
  const float lZ = __logf(S) + mx;
  float ent = 0.f;
#pragma unroll
  for (int j = 0; j < AD; ++j) ent += (ex[j] * inv) * (logits[j] - lZ);
  ent = -ent;
  const float lp_a = logits[action[s]] - lZ;

  if (lane < 10) {
    float v;
    if (lane == 0)      v = lp_a;
    else if (lane == 1) v = ent;
    else if (lane == 2) v = val;
    else                v = ex[lane - 3] * inv;
    out[(size_t)s * 10 + lane] = v;
  }
}

// ================= launch =================
extern "C" void kernel_launch(void* const* d_in, const int* in_sizes, int n_in,
                              void* d_out, int out_size, void* d_ws, size_t ws_size,
                              hipStream_t stream) {
  const float* x       = (const float*)d_in[0];
  const int*   done    = (const int*)d_in[1];
  const int*   z       = (const int*)d_in[2];
  const int*   action  = (const int*)d_in[3];
  const float* h0      = (const float*)d_in[4];
  const float* c0      = (const float*)d_in[5];
  const float* conv1_w = (const float*)d_in[6];
  const float* conv1_b = (const float*)d_in[7];
  const float* conv2_w = (const float*)d_in[8];
  const float* conv2_b = (const float*)d_in[9];
  const float* conv3_w = (const float*)d_in[10];
  const float* conv3_b = (const float*)d_in[11];
  const float* fc1_w   = (const float*)d_in[12];
  const float* fc1_b   = (const float*)d_in[13];
  const float* fc2_w   = (const float*)d_in[14];
  const float* fc2_b   = (const float*)d_in[15];
  const float* w_ih    = (const float*)d_in[16];
  const float* w_hh    = (const float*)d_in[17];
  const float* b_ih    = (const float*)d_in[18];
  const float* b_hh    = (const float*)d_in[19];
  const float* lofeat_w= (const float*)d_in[20];
  const float* lofeat_b= (const float*)d_in[21];
  const float* actor_w = (const float*)d_in[22];
  const float* actor_b = (const float*)d_in[23];
  const float* critic_w= (const float*)d_in[24];
  const float* critic_b= (const float*)d_in[25];
  float* out = (float*)d_out;

  // -------- workspace layout --------
  char* p = (char*)d_ws;
  unsigned short* conv3out = (unsigned short*)p;                 // bf16 TB*4096
  float*          gates    = (float*)p;            p += (size_t)TB * CHW * 2 * 2; // overlay: gates fp32 TB*2048 == same bytes
  unsigned short* fc1out   = (unsigned short*)p;   p += (size_t)TB * HID * 2;
  unsigned short* fc2out   = (unsigned short*)p;   p += (size_t)TB * HID * 2;
  unsigned short* feat     = (unsigned short*)p;   p += (size_t)TB * HID * 2;
  float*          rawlf    = (float*)p;            p += (size_t)TB * FE * 4;
  unsigned short* fc1w_bf  = (unsigned short*)p;   p += (size_t)HID * CHW * 2;
  unsigned short* fc2w_bf  = (unsigned short*)p;   p += (size_t)HID * HID * 2;
  unsigned short* wih_bf   = (unsigned short*)p;   p += (size_t)G4 * HID * 2;
  unsigned short* whh_bf   = (unsigned short*)p;   p += (size_t)G4 * HID * 2;
  unsigned short* lofw_bf  = (unsigned short*)p;   p += (size_t)FE * HID * 2;
  float*          combbias = (float*)p;            p += (size_t)G4 * 4;
  unsigned short* hmA      = (unsigned short*)p;   p += (size_t)BB * HID * 2;
  unsigned short* hmB      = (unsigned short*)p;   p += (size_t)BB * HID * 2;
  float*          cm       = (float*)p;            p += (size_t)BB * HID * 4;

  // 1. fused convs (bf16 out)
  conv_fused_kernel<<<TB, 256, 0, stream>>>(x, conv1_w, conv1_b, conv2_w, conv2_b,
                                            conv3_w, conv3_b, conv3out);
  // 2. weight conversions + bias combine + lstm state init
  f2b_kernel<<<(HID * CHW + 255) / 256, 256, 0, stream>>>(fc1_w, fc1w_bf, HID * CHW);
  f2b_kernel<<<(HID * HID + 255) / 256, 256, 0, stream>>>(fc2_w, fc2w_bf, HID * HID);
  f2b_kernel<<<(G4 * HID + 255) / 256, 256, 0, stream>>>(w_ih, wih_bf, G4 * HID);
  f2b_kernel<<<(G4 * HID + 255) / 256, 256, 0, stream>>>(w_hh, whh_bf, G4 * HID);
  lofpack_kernel<<<(FE * HID + 255) / 256, 256, 0, stream>>>(lofeat_w, lofw_bf);
  bias_add_kernel<<<(G4 + 255) / 256, 256, 0, stream>>>(b_ih, b_hh, combbias, G4);
  lstm_init_kernel<<<(BB * HID + 255) / 256, 256, 0, stream>>>(h0, c0, done, hmA, cm);
  // 3. fc1: [TB,4096] x [512,4096]^T -> bf16
  mfma_fc<true, true><<<dim3(HID / 128, TB / 128), 256, 0, stream>>>(
      conv3out, fc1w_bf, fc1_b, fc1out, CHW, HID);
  // 4. fc2: [TB,512] x [512,512]^T -> bf16
  mfma_fc<true, true><<<dim3(HID / 128, TB / 128), 256, 0, stream>>>(
      fc1out, fc2w_bf, fc2_b, fc2out, HID, HID);
  // 5. gates_ih: [TB,512] x [2048,512]^T + (b_ih+b_hh) -> fp32 (overlays conv3out)
  mfma_fc<false, false><<<dim3(G4 / 128, TB / 128), 256, 0, stream>>>(
      fc2out, wih_bf, combbias, gates, HID, G4);
  // 6. LSTM: 128 fused MFMA steps, h ping-pong (pre-masked bf16), c in-place fp32
  for (int t = 0; t < TT; ++t) {
    const unsigned short* hr = (t & 1) ? hmB : hmA;
    unsigned short* hw = (t & 1) ? hmA : hmB;
    const int tn = (t < TT - 1) ? t + 1 : t;
    lstm_step<<<16, 256, 0, stream>>>(
        gates + (size_t)t * BB * G4, whh_bf, hr, cm,
        done + (size_t)tn * BB, hw, feat + (size_t)t * BB * HID);
  }
  // 7. lofeat raw: [TB,512] x [128,512]^T -> fp32 (bias/z-col/leaky in heads)
  mfma_fc<false, false><<<dim3(FE / 128, TB / 128), 256, 0, stream>>>(
      feat, lofw_bf, nullptr, rawlf, HID, FE);
  // 8. heads
  heads_kernel<<<TB / 4, 256, 0, stream>>>(rawlf, lofeat_w, lofeat_b, actor_w, actor_b,
                                           critic_w, critic_b, z, action, out);
}

// Round 3
// 2908.042 us; speedup vs baseline: 4.0843x; 1.8468x over previous
//
#include <hip/hip_runtime.h>
#include <hip/hip_bf16.h>
#include <math.h>

// ---------------- problem dims ----------------
#define TT   128
#define BB   128
#define TB   (TT*BB)         // 16384
#define CHW  4096
#define HID  512
#define G4   2048            // 4*HID
#define ZD   8
#define AD   7
#define FE   128
#define LOFK 520             // HID + ZD

typedef __attribute__((ext_vector_type(8))) short short8;
typedef __attribute__((ext_vector_type(4))) float f32x4;

__device__ __forceinline__ unsigned short f2b(float f) {
  unsigned int u = __float_as_uint(f);
  unsigned int r = (u + 0x7FFFu + ((u >> 16) & 1u)) >> 16;
  return (unsigned short)r;
}

__device__ __forceinline__ void glds16(const void* g, void* l) {
  __builtin_amdgcn_global_load_lds((const __attribute__((address_space(1))) void*)g,
                                   (__attribute__((address_space(3))) void*)l, 16, 0, 0);
}

// ============================================================================
// Conv as implicit-GEMM MFMA. One block per image, 4 waves.
// LDS image layout: [ci_hi(2)][yy(20)][xx(20)][ci_lo(8)] bf16, pad=2 halo.
//   -> pixel stride 16 B => conflict-free-ish ds_read_b128 A-frags.
// Weights pre-packed: Bp[co][k], k = tap*16+ci, K padded to mult of 32.
//   A-frag (16x16x32): lane l16 = x, k = quad*8+j -> tap t = 2s+(quad>>1),
//   ci = (quad&1)*8+j -> one b128 at img[(quad&1)][y+ky][x+kx][0..7].
// ============================================================================
__global__ __launch_bounds__(256) void conv_mfma_kernel(
    const float* __restrict__ x,
    const unsigned short* __restrict__ bp1, const unsigned short* __restrict__ bp2,
    const unsigned short* __restrict__ bp3,
    const float* __restrict__ b1, const float* __restrict__ b2, const float* __restrict__ b3,
    unsigned short* __restrict__ out)
{
  __shared__ unsigned short img[2 * 6400];   // two 20*20*16 bf16 buffers
  const int tid = threadIdx.x;
  const int wv = tid >> 6, lane = tid & 63, quad = lane >> 4, l16 = lane & 15;
  const int imgid = blockIdx.x;
  unsigned short* buf0 = img;
  unsigned short* buf1 = img + 6400;

  // zero both buffers (halo must be 0)
  {
    int4 z = {0, 0, 0, 0};
    for (int i = tid; i < 1600; i += 256) ((int4*)img)[i] = z;
  }
  __syncthreads();
  // load input fp32 NCHW -> bf16 channel-split-last, pad2
  const float* src = x + (size_t)imgid * CHW;
  for (int i = tid; i < CHW; i += 256) {
    const int ci = i >> 8, rem = i & 255, y = rem >> 4, xx = rem & 15;
    buf0[(((ci >> 3) * 400) + (y + 2) * 20 + (xx + 2)) * 8 + (ci & 7)] = f2b(src[i]);
  }
  __syncthreads();

  // ---- stage 1: 5x5, K=416 (13 k-steps), pad tap 25 -> (4,4) w/ zero B ----
  {
    short8 bf[13];
#pragma unroll
    for (int s = 0; s < 13; ++s)
      bf[s] = *(const short8*)(bp1 + l16 * 416 + s * 32 + quad * 8);
    f32x4 acc[4];
#pragma unroll
    for (int mt = 0; mt < 4; ++mt)
#pragma unroll
      for (int r = 0; r < 4; ++r) acc[mt][r] = 0.f;
#pragma unroll
    for (int s = 0; s < 13; ++s) {
      int t = 2 * s + (quad >> 1); if (t > 24) t = 24;
      const int ky = t / 5, kx = t - ky * 5;
      const int base = ((quad & 1) * 400 + ky * 20 + l16 + kx) * 8;
#pragma unroll
      for (int mt = 0; mt < 4; ++mt) {
        const int y = wv * 4 + mt;
        short8 a = *(const short8*)&buf0[base + y * 160];
        acc[mt] = __builtin_amdgcn_mfma_f32_16x16x32_bf16(a, bf[s], acc[mt], 0, 0, 0);
      }
    }
    const float bias = b1[l16];
#pragma unroll
    for (int mt = 0; mt < 4; ++mt) {
      const int y = wv * 4 + mt;
#pragma unroll
      for (int r = 0; r < 4; ++r) {
        float v = acc[mt][r] + bias;
        v = v > 0.f ? v : 0.01f * v;
        const int xx = quad * 4 + r;
        buf1[(((l16 >> 3) * 400) + (y + 2) * 20 + (xx + 2)) * 8 + (l16 & 7)] = f2b(v);
      }
    }
  }
  __syncthreads();

  // ---- stage 2: 3x3, K=160 (5 k-steps), pad tap 9 -> (2,2) zero B ----
  {
    short8 bf[5];
#pragma unroll
    for (int s = 0; s < 5; ++s)
      bf[s] = *(const short8*)(bp2 + l16 * 160 + s * 32 + quad * 8);
    f32x4 acc[4];
#pragma unroll
    for (int mt = 0; mt < 4; ++mt)
#pragma unroll
      for (int r = 0; r < 4; ++r) acc[mt][r] = 0.f;
#pragma unroll
    for (int s = 0; s < 5; ++s) {
      int t = 2 * s + (quad >> 1); if (t > 8) t = 8;
      const int ky = t / 3, kx = t - ky * 3;
      const int base = ((quad & 1) * 400 + (ky + 1) * 20 + l16 + kx + 1) * 8;
#pragma unroll
      for (int mt = 0; mt < 4; ++mt) {
        const int y = wv * 4 + mt;
        short8 a = *(const short8*)&buf1[base + y * 160];
        acc[mt] = __builtin_amdgcn_mfma_f32_16x16x32_bf16(a, bf[s], acc[mt], 0, 0, 0);
      }
    }
    const float bias = b2[l16];
#pragma unroll
    for (int mt = 0; mt < 4; ++mt) {
      const int y = wv * 4 + mt;
#pragma unroll
      for (int r = 0; r < 4; ++r) {
        float v = acc[mt][r] + bias;
        v = v > 0.f ? v : 0.01f * v;
        const int xx = quad * 4 + r;
        buf0[(((l16 >> 3) * 400) + (y + 2) * 20 + (xx + 2)) * 8 + (l16 & 7)] = f2b(v);
      }
    }
  }
  __syncthreads();

  // ---- stage 3: 3x3 -> global bf16 NCHW ----
  {
    short8 bf[5];
#pragma unroll
    for (int s = 0; s < 5; ++s)
      bf[s] = *(const short8*)(bp3 + l16 * 160 + s * 32 + quad * 8);
    f32x4 acc[4];
#pragma unroll
    for (int mt = 0; mt < 4; ++mt)
#pragma unroll
      for (int r = 0; r < 4; ++r) acc[mt][r] = 0.f;
#pragma unroll
    for (int s = 0; s < 5; ++s) {
      int t = 2 * s + (quad >> 1); if (t > 8) t = 8;
      const int ky = t / 3, kx = t - ky * 3;
      const int base = ((quad & 1) * 400 + (ky + 1) * 20 + l16 + kx + 1) * 8;
#pragma unroll
      for (int mt = 0; mt < 4; ++mt) {
        const int y = wv * 4 + mt;
        short8 a = *(const short8*)&buf0[base + y * 160];
        acc[mt] = __builtin_amdgcn_mfma_f32_16x16x32_bf16(a, bf[s], acc[mt], 0, 0, 0);
      }
    }
    const float bias = b3[l16];
    unsigned short* dst = out + (size_t)imgid * CHW;
#pragma unroll
    for (int mt = 0; mt < 4; ++mt) {
      const int y = wv * 4 + mt;
      ushort4 pk;
      float v;
      v = acc[mt][0] + bias; v = v > 0.f ? v : 0.01f * v; pk.x = f2b(v);
      v = acc[mt][1] + bias; v = v > 0.f ? v : 0.01f * v; pk.y = f2b(v);
      v = acc[mt][2] + bias; v = v > 0.f ? v : 0.01f * v; pk.z = f2b(v);
      v = acc[mt][3] + bias; v = v > 0.f ? v : 0.01f * v; pk.w = f2b(v);
      *(ushort4*)(dst + l16 * 256 + y * 16 + quad * 4) = pk;
    }
  }
}

// pack conv weights OIHW fp32 -> Bp[co][k] bf16, k = tap*16+ci, K mult of 32
__global__ void pack_convw(const float* __restrict__ w, unsigned short* __restrict__ bp,
                           int K, int KH) {
  int i = blockIdx.x * 256 + threadIdx.x;
  if (i >= 16 * K) return;
  int co = i / K, k = i - co * K;
  int t = k >> 4, ci = k & 15;
  float v = 0.f;
  if (t < KH * KH) v = w[((co * 16 + ci) * KH + t / KH) * KH + t % KH];
  bp[i] = f2b(v);
}

// ================= bf16 MFMA GEMM (verified R2): out[N,M] = act(A@W^T + bias) =================
template<bool LEAKY, bool OUTBF>
__global__ __launch_bounds__(256) void mfma_fc(
    const unsigned short* __restrict__ A, const unsigned short* __restrict__ W,
    const float* __restrict__ bias, void* __restrict__ outp, int K, int M) {
  __shared__ unsigned short As[128 * 32];
  __shared__ unsigned short Bs[128 * 32];
  const int tid = threadIdx.x;
  const int wv = tid >> 6, lane = tid & 63;
  const int quad = lane >> 4, l16 = lane & 15;
  const int wr = (wv >> 1) * 64, wc = (wv & 1) * 64;
  const int rb = blockIdx.y * 128, cb = blockIdx.x * 128;

  const int s0 = tid, s1 = tid + 256;
  const int r0 = s0 >> 2, q0 = s0 & 3;
  const int r1 = s1 >> 2, q1 = s1 & 3;
  const unsigned short* A0 = A + (size_t)(rb + r0) * K + q0 * 8;
  const unsigned short* A1 = A + (size_t)(rb + r1) * K + q1 * 8;
  const unsigned short* W0 = W + (size_t)(cb + r0) * K + q0 * 8;
  const unsigned short* W1 = W + (size_t)(cb + r1) * K + q1 * 8;
  void* ldsA0 = (void*)&As[(wv * 64) * 8];
  void* ldsA1 = (void*)&As[(256 + wv * 64) * 8];
  void* ldsB0 = (void*)&Bs[(wv * 64) * 8];
  void* ldsB1 = (void*)&Bs[(256 + wv * 64) * 8];

  f32x4 acc[4][4];
#pragma unroll
  for (int i = 0; i < 4; ++i)
#pragma unroll
    for (int j = 0; j < 4; ++j)
#pragma unroll
      for (int r = 0; r < 4; ++r) acc[i][j][r] = 0.f;

  for (int k0 = 0; k0 < K; k0 += 32) {
    glds16(A0 + k0, ldsA0);
    glds16(A1 + k0, ldsA1);
    glds16(W0 + k0, ldsB0);
    glds16(W1 + k0, ldsB1);
    __syncthreads();
    short8 af[4], bfr[4];
#pragma unroll
    for (int i = 0; i < 4; ++i)
      af[i] = *(const short8*)&As[(wr + i * 16 + l16) * 32 + quad * 8];
#pragma unroll
    for (int j = 0; j < 4; ++j)
      bfr[j] = *(const short8*)&Bs[(wc + j * 16 + l16) * 32 + quad * 8];
#pragma unroll
    for (int i = 0; i < 4; ++i)
#pragma unroll
      for (int j = 0; j < 4; ++j)
        acc[i][j] = __builtin_amdgcn_mfma_f32_16x16x32_bf16(af[i], bfr[j], acc[i][j], 0, 0, 0);
    __syncthreads();
  }

#pragma unroll
  for (int j = 0; j < 4; ++j) {
    const int col = cb + wc + j * 16 + l16;
    const float bj = bias ? bias[col] : 0.f;
#pragma unroll
    for (int i = 0; i < 4; ++i) {
#pragma unroll
      for (int r = 0; r < 4; ++r) {
        const size_t row = rb + wr + i * 16 + quad * 4 + r;
        float v = acc[i][j][r] + bj;
        if (LEAKY) v = v > 0.f ? v : 0.01f * v;
        if (OUTBF) ((unsigned short*)outp)[row * M + col] = f2b(v);
        else       ((float*)outp)[row * M + col] = v;
      }
    }
  }
}

// ============================================================================
// Persistent LSTM: 32 blocks x 256 thr, all 128 timesteps in one launch.
// Block bid owns j-slice [j0, j0+16); computes 128(batch) x 64(= 4 gates x 16 j)
// MFMA tile per step. w_hh slice resident in LDS (row-padded to 520 to break
// the 1KB-stride bank aliasing). h(t) read directly from L2 (no staging
// barriers). Column order c = gate*16+j => all 4 gates land in the SAME lane's
// accumulators -> register-only cell epilogue. Grid barrier: monotonic
// device-scope atomic counter + __threadfence (32 blocks always co-resident).
// ============================================================================
__global__ __launch_bounds__(256) void lstm_persistent(
    const float* __restrict__ gih_all,       // [T][128][2048] fp32
    const unsigned short* __restrict__ whh,  // bf16 [2048][512]
    unsigned short* __restrict__ h0m,        // ping (pre-masked bf16), read at even t
    unsigned short* __restrict__ h1m,        // pong
    float* __restrict__ cm,                  // fp32 [128][512] pre-masked
    const int* __restrict__ done,            // [T][128]
    unsigned short* __restrict__ feat,       // bf16 [T][128][512] unmasked h
    int* __restrict__ barcnt)
{
  __shared__ unsigned short whs[64][520];
  const int tid = threadIdx.x, wv = tid >> 6, lane = tid & 63;
  const int quad = lane >> 4, l16 = lane & 15;
  const int j0 = blockIdx.x * 16;

  // preload w_hh slice: row rr -> gate g=rr>>4, j=j0+(rr&15)
  for (int rr = wv; rr < 64; rr += 4) {
    const int g = rr >> 4, jj = rr & 15;
    const unsigned short* srcp = whh + ((size_t)(g * HID + j0 + jj)) * HID + lane * 8;
    *(short8*)&whs[rr][lane * 8] = *(const short8*)srcp;
  }
  __syncthreads();

  for (int t = 0; t < TT; ++t) {
    const unsigned short* hc = (t & 1) ? h1m : h0m;
    unsigned short* hn = (t & 1) ? h0m : h1m;
    const float* gih = gih_all + (size_t)t * BB * G4;

    f32x4 acc[2][4];
#pragma unroll
    for (int i = 0; i < 2; ++i)
#pragma unroll
      for (int g = 0; g < 4; ++g)
#pragma unroll
        for (int r = 0; r < 4; ++r) acc[i][g][r] = 0.f;

#pragma unroll 8
    for (int kk = 0; kk < 16; ++kk) {
      short8 a0 = *(const short8*)(hc + (size_t)(wv * 32 + l16) * HID + kk * 32 + quad * 8);
      short8 a1 = *(const short8*)(hc + (size_t)(wv * 32 + 16 + l16) * HID + kk * 32 + quad * 8);
      short8 b0 = *(const short8*)&whs[l16][kk * 32 + quad * 8];
      short8 b1 = *(const short8*)&whs[16 + l16][kk * 32 + quad * 8];
      short8 b2 = *(const short8*)&whs[32 + l16][kk * 32 + quad * 8];
      short8 b3 = *(const short8*)&whs[48 + l16][kk * 32 + quad * 8];
      acc[0][0] = __builtin_amdgcn_mfma_f32_16x16x32_bf16(a0, b0, acc[0][0], 0, 0, 0);
      acc[0][1] = __builtin_amdgcn_mfma_f32_16x16x32_bf16(a0, b1, acc[0][1], 0, 0, 0);
      acc[0][2] = __builtin_amdgcn_mfma_f32_16x16x32_bf16(a0, b2, acc[0][2], 0, 0, 0);
      acc[0][3] = __builtin_amdgcn_mfma_f32_16x16x32_bf16(a0, b3, acc[0][3], 0, 0, 0);
      acc[1][0] = __builtin_amdgcn_mfma_f32_16x16x32_bf16(a1, b0, acc[1][0], 0, 0, 0);
      acc[1][1] = __builtin_amdgcn_mfma_f32_16x16x32_bf16(a1, b1, acc[1][1], 0, 0, 0);
      acc[1][2] = __builtin_amdgcn_mfma_f32_16x16x32_bf16(a1, b2, acc[1][2], 0, 0, 0);
      acc[1][3] = __builtin_amdgcn_mfma_f32_16x16x32_bf16(a1, b3, acc[1][3], 0, 0, 0);
    }

    // epilogue: all 4 gates for (b, j) live in this lane's accumulators
    const int tn = (t < TT - 1) ? t + 1 : t;
    const int* dn = done + (size_t)tn * BB;
    const int j = j0 + l16;
#pragma unroll
    for (int i = 0; i < 2; ++i) {
#pragma unroll
      for (int r = 0; r < 4; ++r) {
        const int b = wv * 32 + i * 16 + quad * 4 + r;
        const size_t gb = (size_t)b * G4 + j;
        const float gi = acc[i][0][r] + gih[gb];
        const float gf = acc[i][1][r] + gih[gb + HID];
        const float gg = acc[i][2][r] + gih[gb + 2 * HID];
        const float go = acc[i][3][r] + gih[gb + 3 * HID];
        const float c_old = cm[(size_t)b * HID + j];
        const float i_s = 1.f / (1.f + __expf(-gi));
        const float f_s = 1.f / (1.f + __expf(-gf));
        const float o_s = 1.f / (1.f + __expf(-go));
        const float g_t = tanhf(gg);
        const float c_new = f_s * c_old + i_s * g_t;
        const float h_new = o_s * tanhf(c_new);
        const float mn = 1.f - (float)dn[b];
        cm[(size_t)b * HID + j] = c_new * mn;
        hn[(size_t)b * HID + j] = f2b(h_new * mn);
        feat[((size_t)t * BB + b) * HID + j] = f2b(h_new);
      }
    }

    if (t < TT - 1) {
      __threadfence();          // release: h(t+1)/c visible device-wide
      __syncthreads();
      if (tid == 0) {
        atomicAdd(barcnt, 1);
        const int target = 32 * (t + 1);
        while (__hip_atomic_load(barcnt, __ATOMIC_RELAXED, __HIP_MEMORY_SCOPE_AGENT) < target)
          __builtin_amdgcn_s_sleep(4);
      }
      __syncthreads();
      __threadfence();          // acquire: invalidate stale L1/L2
    }
  }
}

// ================= small prep kernels =================
__global__ void f2b_kernel(const float* __restrict__ in, unsigned short* __restrict__ out, int n) {
  int i = blockIdx.x * 256 + threadIdx.x;
  if (i < n) out[i] = f2b(in[i]);
}
__global__ void lofpack_kernel(const float* __restrict__ lw, unsigned short* __restrict__ out) {
  int i = blockIdx.x * 256 + threadIdx.x;  // 65536
  int r = i >> 9, c = i & 511;
  out[i] = f2b(lw[r * LOFK + c]);
}
__global__ void bias_add_kernel(const float* __restrict__ a, const float* __restrict__ b,
                                float* __restrict__ o, int n) {
  int i = blockIdx.x * 256 + threadIdx.x;
  if (i < n) o[i] = a[i] + b[i];
}
__global__ void lstm_init_kernel(const float* __restrict__ h0, const float* __restrict__ c0,
                                 const int* __restrict__ done0,
                                 unsigned short* __restrict__ hm, float* __restrict__ cmp) {
  int i = blockIdx.x * 256 + threadIdx.x;  // 65536
  int b = i >> 9;
  float m = 1.f - (float)done0[b];
  hm[i] = f2b(h0[i] * m);
  cmp[i] = c0[i] * m;
}

// ================= heads =================
__global__ __launch_bounds__(256) void heads_kernel(
    const float* __restrict__ raw, const float* __restrict__ lw, const float* __restrict__ lb,
    const float* __restrict__ aw, const float* __restrict__ ab,
    const float* __restrict__ cw, const float* __restrict__ cbias,
    const int* __restrict__ z, const int* __restrict__ action,
    float* __restrict__ out) {
  const int lane = threadIdx.x & 63;
  const int s = blockIdx.x * 4 + (threadIdx.x >> 6);
  const int zv = z[s];
  float v0 = raw[(size_t)s * FE + lane]      + lw[(size_t)lane * LOFK + HID + zv]        + lb[lane];
  float v1 = raw[(size_t)s * FE + 64 + lane] + lw[(size_t)(64 + lane) * LOFK + HID + zv] + lb[64 + lane];
  v0 = v0 > 0.f ? v0 : 0.01f * v0;
  v1 = v1 > 0.f ? v1 : 0.01f * v1;

  float logits[AD];
#pragma unroll
  for (int j = 0; j < AD; ++j) {
    float p = aw[j * FE + lane] * v0 + aw[j * FE + 64 + lane] * v1;
#pragma unroll
    for (int o = 32; o > 0; o >>= 1) p += __shfl_down(p, o, 64);
    logits[j] = __shfl(p, 0, 64) + ab[j];
  }
  float val = cw[lane] * v0 + cw[64 + lane] * v1;
#pragma unroll
  for (int o = 32; o > 0; o >>= 1) val += __shfl_down(val, o, 64);
  val = __shfl(val, 0, 64) + cbias[0];

  float mx = logits[0];
#pragma unroll
  for (int j = 1; j < AD; ++j) mx = fmaxf(mx, logits[j]);
  float ex[AD], S = 0.f;
#pragma unroll
  for (int j = 0; j < AD; ++j) { ex[j] = __expf(logits[j] - mx); S += ex[j]; }
  const float inv = 1.f / S;
  const float lZ = __logf(S) + mx;
  float ent = 0.f;
#pragma unroll
  for (int j = 0; j < AD; ++j) ent += (ex[j] * inv) * (logits[j] - lZ);
  ent = -ent;
  const float lp_a = logits[action[s]] - lZ;

  if (lane < 10) {
    float v;
    if (lane == 0)      v = lp_a;
    else if (lane == 1) v = ent;
    else if (lane == 2) v = val;
    else                v = ex[lane - 3] * inv;
    out[(size_t)s * 10 + lane] = v;
  }
}

// ================= launch =================
extern "C" void kernel_launch(void* const* d_in, const int* in_sizes, int n_in,
                              void* d_out, int out_size, void* d_ws, size_t ws_size,
                              hipStream_t stream) {
  const float* x       = (const float*)d_in[0];
  const int*   done    = (const int*)d_in[1];
  const int*   z       = (const int*)d_in[2];
  const int*   action  = (const int*)d_in[3];
  const float* h0      = (const float*)d_in[4];
  const float* c0      = (const float*)d_in[5];
  const float* conv1_w = (const float*)d_in[6];
  const float* conv1_b = (const float*)d_in[7];
  const float* conv2_w = (const float*)d_in[8];
  const float* conv2_b = (const float*)d_in[9];
  const float* conv3_w = (const float*)d_in[10];
  const float* conv3_b = (const float*)d_in[11];
  const float* fc1_w   = (const float*)d_in[12];
  const float* fc1_b   = (const float*)d_in[13];
  const float* fc2_w   = (const float*)d_in[14];
  const float* fc2_b   = (const float*)d_in[15];
  const float* w_ih    = (const float*)d_in[16];
  const float* w_hh    = (const float*)d_in[17];
  const float* b_ih    = (const float*)d_in[18];
  const float* b_hh    = (const float*)d_in[19];
  const float* lofeat_w= (const float*)d_in[20];
  const float* lofeat_b= (const float*)d_in[21];
  const float* actor_w = (const float*)d_in[22];
  const float* actor_b = (const float*)d_in[23];
  const float* critic_w= (const float*)d_in[24];
  const float* critic_b= (const float*)d_in[25];
  float* out = (float*)d_out;

  // -------- workspace layout --------
  char* p = (char*)d_ws;
  unsigned short* conv3out = (unsigned short*)p;                 // bf16 TB*4096
  float*          gates    = (float*)p;            p += (size_t)TB * CHW * 2;  // == TB*2048*4 overlay
  unsigned short* fc1out   = (unsigned short*)p;   p += (size_t)TB * HID * 2;
  unsigned short* fc2out   = (unsigned short*)p;   p += (size_t)TB * HID * 2;
  unsigned short* feat     = (unsigned short*)p;   p += (size_t)TB * HID * 2;
  float*          rawlf    = (float*)p;            p += (size_t)TB * FE * 4;
  unsigned short* fc1w_bf  = (unsigned short*)p;   p += (size_t)HID * CHW * 2;
  unsigned short* fc2w_bf  = (unsigned short*)p;   p += (size_t)HID * HID * 2;
  unsigned short* wih_bf   = (unsigned short*)p;   p += (size_t)G4 * HID * 2;
  unsigned short* whh_bf   = (unsigned short*)p;   p += (size_t)G4 * HID * 2;
  unsigned short* lofw_bf  = (unsigned short*)p;   p += (size_t)FE * HID * 2;
  unsigned short* bp1      = (unsigned short*)p;   p += 16 * 416 * 2;
  unsigned short* bp2      = (unsigned short*)p;   p += 16 * 160 * 2;
  unsigned short* bp3      = (unsigned short*)p;   p += 16 * 160 * 2;
  float*          combbias = (float*)p;            p += (size_t)G4 * 4;
  unsigned short* hmA      = (unsigned short*)p;   p += (size_t)BB * HID * 2;
  unsigned short* hmB      = (unsigned short*)p;   p += (size_t)BB * HID * 2;
  float*          cm       = (float*)p;            p += (size_t)BB * HID * 4;
  int*            barcnt   = (int*)p;              p += 64;

  // 0. barrier counter must start at 0 (ws is poisoned 0xAA)
  hipMemsetAsync(barcnt, 0, 4, stream);
  // 1. weight packing / conversions
  pack_convw<<<26, 256, 0, stream>>>(conv1_w, bp1, 416, 5);
  pack_convw<<<10, 256, 0, stream>>>(conv2_w, bp2, 160, 3);
  pack_convw<<<10, 256, 0, stream>>>(conv3_w, bp3, 160, 3);
  f2b_kernel<<<(HID * CHW + 255) / 256, 256, 0, stream>>>(fc1_w, fc1w_bf, HID * CHW);
  f2b_kernel<<<(HID * HID + 255) / 256, 256, 0, stream>>>(fc2_w, fc2w_bf, HID * HID);
  f2b_kernel<<<(G4 * HID + 255) / 256, 256, 0, stream>>>(w_ih, wih_bf, G4 * HID);
  f2b_kernel<<<(G4 * HID + 255) / 256, 256, 0, stream>>>(w_hh, whh_bf, G4 * HID);
  lofpack_kernel<<<(FE * HID + 255) / 256, 256, 0, stream>>>(lofeat_w, lofw_bf);
  bias_add_kernel<<<(G4 + 255) / 256, 256, 0, stream>>>(b_ih, b_hh, combbias, G4);
  lstm_init_kernel<<<(BB * HID + 255) / 256, 256, 0, stream>>>(h0, c0, done, hmA, cm);
  // 2. conv stack (MFMA implicit GEMM), bf16 out
  conv_mfma_kernel<<<TB, 256, 0, stream>>>(x, bp1, bp2, bp3,
                                           conv1_b, conv2_b, conv3_b, conv3out);
  // 3. fc1: [TB,4096] x [512,4096]^T -> bf16
  mfma_fc<true, true><<<dim3(HID / 128, TB / 128), 256, 0, stream>>>(
      conv3out, fc1w_bf, fc1_b, fc1out, CHW, HID);
  // 4. fc2
  mfma_fc<true, true><<<dim3(HID / 128, TB / 128), 256, 0, stream>>>(
      fc1out, fc2w_bf, fc2_b, fc2out, HID, HID);
  // 5. gates_ih (+ combined bias) -> fp32, overlays conv3out
  mfma_fc<false, false><<<dim3(G4 / 128, TB / 128), 256, 0, stream>>>(
      fc2out, wih_bf, combbias, gates, HID, G4);
  // 6. LSTM: single persistent kernel, 128 steps, grid barrier between steps
  lstm_persistent<<<32, 256, 0, stream>>>(gates, whh_bf, hmA, hmB, cm, done, feat, barcnt);
  // 7. lofeat raw GEMM
  mfma_fc<false, false><<<dim3(FE / 128, TB / 128), 256, 0, stream>>>(
      feat, lofw_bf, nullptr, rawlf, HID, FE);
  // 8. heads
  heads_kernel<<<TB / 4, 256, 0, stream>>>(rawlf, lofeat_w, lofeat_b, actor_w, actor_b,
                                           critic_w, critic_b, z, action, out);
}

// Round 4
// 2336.862 us; speedup vs baseline: 5.0826x; 1.2444x over previous
//
#include <hip/hip_runtime.h>
#include <hip/hip_bf16.h>
#include <math.h>

// ---------------- problem dims ----------------
#define TT   128
#define BB   128
#define TB   (TT*BB)         // 16384
#define CHW  4096
#define HID  512
#define G4   2048            // 4*HID
#define ZD   8
#define AD   7
#define FE   128
#define LOFK 520             // HID + ZD

typedef __attribute__((ext_vector_type(8))) short short8;
typedef __attribute__((ext_vector_type(4))) float f32x4;

__device__ __forceinline__ unsigned short f2b(float f) {
  unsigned int u = __float_as_uint(f);
  unsigned int r = (u + 0x7FFFu + ((u >> 16) & 1u)) >> 16;
  return (unsigned short)r;
}

__device__ __forceinline__ void glds16(const void* g, void* l) {
  __builtin_amdgcn_global_load_lds((const __attribute__((address_space(1))) void*)g,
                                   (__attribute__((address_space(3))) void*)l, 16, 0, 0);
}

// ============================================================================
// Conv as implicit-GEMM MFMA (verified R3). One block per image, 4 waves.
// ============================================================================
__global__ __launch_bounds__(256) void conv_mfma_kernel(
    const float* __restrict__ x,
    const unsigned short* __restrict__ bp1, const unsigned short* __restrict__ bp2,
    const unsigned short* __restrict__ bp3,
    const float* __restrict__ b1, const float* __restrict__ b2, const float* __restrict__ b3,
    unsigned short* __restrict__ out)
{
  __shared__ unsigned short img[2 * 6400];   // two 20*20*16 bf16 buffers
  const int tid = threadIdx.x;
  const int wv = tid >> 6, lane = tid & 63, quad = lane >> 4, l16 = lane & 15;
  const int imgid = blockIdx.x;
  unsigned short* buf0 = img;
  unsigned short* buf1 = img + 6400;

  {
    int4 z = {0, 0, 0, 0};
    for (int i = tid; i < 1600; i += 256) ((int4*)img)[i] = z;
  }
  __syncthreads();
  const float* src = x + (size_t)imgid * CHW;
  for (int i = tid; i < CHW; i += 256) {
    const int ci = i >> 8, rem = i & 255, y = rem >> 4, xx = rem & 15;
    buf0[(((ci >> 3) * 400) + (y + 2) * 20 + (xx + 2)) * 8 + (ci & 7)] = f2b(src[i]);
  }
  __syncthreads();

  // ---- stage 1: 5x5, K=416 ----
  {
    short8 bf[13];
#pragma unroll
    for (int s = 0; s < 13; ++s)
      bf[s] = *(const short8*)(bp1 + l16 * 416 + s * 32 + quad * 8);
    f32x4 acc[4];
#pragma unroll
    for (int mt = 0; mt < 4; ++mt)
#pragma unroll
      for (int r = 0; r < 4; ++r) acc[mt][r] = 0.f;
#pragma unroll
    for (int s = 0; s < 13; ++s) {
      int t = 2 * s + (quad >> 1); if (t > 24) t = 24;
      const int ky = t / 5, kx = t - ky * 5;
      const int base = ((quad & 1) * 400 + ky * 20 + l16 + kx) * 8;
#pragma unroll
      for (int mt = 0; mt < 4; ++mt) {
        const int y = wv * 4 + mt;
        short8 a = *(const short8*)&buf0[base + y * 160];
        acc[mt] = __builtin_amdgcn_mfma_f32_16x16x32_bf16(a, bf[s], acc[mt], 0, 0, 0);
      }
    }
    const float bias = b1[l16];
#pragma unroll
    for (int mt = 0; mt < 4; ++mt) {
      const int y = wv * 4 + mt;
#pragma unroll
      for (int r = 0; r < 4; ++r) {
        float v = acc[mt][r] + bias;
        v = v > 0.f ? v : 0.01f * v;
        const int xx = quad * 4 + r;
        buf1[(((l16 >> 3) * 400) + (y + 2) * 20 + (xx + 2)) * 8 + (l16 & 7)] = f2b(v);
      }
    }
  }
  __syncthreads();

  // ---- stage 2: 3x3, K=160 ----
  {
    short8 bf[5];
#pragma unroll
    for (int s = 0; s < 5; ++s)
      bf[s] = *(const short8*)(bp2 + l16 * 160 + s * 32 + quad * 8);
    f32x4 acc[4];
#pragma unroll
    for (int mt = 0; mt < 4; ++mt)
#pragma unroll
      for (int r = 0; r < 4; ++r) acc[mt][r] = 0.f;
#pragma unroll
    for (int s = 0; s < 5; ++s) {
      int t = 2 * s + (quad >> 1); if (t > 8) t = 8;
      const int ky = t / 3, kx = t - ky * 3;
      const int base = ((quad & 1) * 400 + (ky + 1) * 20 + l16 + kx + 1) * 8;
#pragma unroll
      for (int mt = 0; mt < 4; ++mt) {
        const int y = wv * 4 + mt;
        short8 a = *(const short8*)&buf1[base + y * 160];
        acc[mt] = __builtin_amdgcn_mfma_f32_16x16x32_bf16(a, bf[s], acc[mt], 0, 0, 0);
      }
    }
    const float bias = b2[l16];
#pragma unroll
    for (int mt = 0; mt < 4; ++mt) {
      const int y = wv * 4 + mt;
#pragma unroll
      for (int r = 0; r < 4; ++r) {
        float v = acc[mt][r] + bias;
        v = v > 0.f ? v : 0.01f * v;
        const int xx = quad * 4 + r;
        buf0[(((l16 >> 3) * 400) + (y + 2) * 20 + (xx + 2)) * 8 + (l16 & 7)] = f2b(v);
      }
    }
  }
  __syncthreads();

  // ---- stage 3: 3x3 -> global bf16 NCHW ----
  {
    short8 bf[5];
#pragma unroll
    for (int s = 0; s < 5; ++s)
      bf[s] = *(const short8*)(bp3 + l16 * 160 + s * 32 + quad * 8);
    f32x4 acc[4];
#pragma unroll
    for (int mt = 0; mt < 4; ++mt)
#pragma unroll
      for (int r = 0; r < 4; ++r) acc[mt][r] = 0.f;
#pragma unroll
    for (int s = 0; s < 5; ++s) {
      int t = 2 * s + (quad >> 1); if (t > 8) t = 8;
      const int ky = t / 3, kx = t - ky * 3;
      const int base = ((quad & 1) * 400 + (ky + 1) * 20 + l16 + kx + 1) * 8;
#pragma unroll
      for (int mt = 0; mt < 4; ++mt) {
        const int y = wv * 4 + mt;
        short8 a = *(const short8*)&buf0[base + y * 160];
        acc[mt] = __builtin_amdgcn_mfma_f32_16x16x32_bf16(a, bf[s], acc[mt], 0, 0, 0);
      }
    }
    const float bias = b3[l16];
    unsigned short* dst = out + (size_t)imgid * CHW;
#pragma unroll
    for (int mt = 0; mt < 4; ++mt) {
      const int y = wv * 4 + mt;
      ushort4 pk;
      float v;
      v = acc[mt][0] + bias; v = v > 0.f ? v : 0.01f * v; pk.x = f2b(v);
      v = acc[mt][1] + bias; v = v > 0.f ? v : 0.01f * v; pk.y = f2b(v);
      v = acc[mt][2] + bias; v = v > 0.f ? v : 0.01f * v; pk.z = f2b(v);
      v = acc[mt][3] + bias; v = v > 0.f ? v : 0.01f * v; pk.w = f2b(v);
      *(ushort4*)(dst + l16 * 256 + y * 16 + quad * 4) = pk;
    }
  }
}

// pack conv weights OIHW fp32 -> Bp[co][k] bf16, k = tap*16+ci, K mult of 32
__global__ void pack_convw(const float* __restrict__ w, unsigned short* __restrict__ bp,
                           int K, int KH) {
  int i = blockIdx.x * 256 + threadIdx.x;
  if (i >= 16 * K) return;
  int co = i / K, k = i - co * K;
  int t = k >> 4, ci = k & 15;
  float v = 0.f;
  if (t < KH * KH) v = w[((co * 16 + ci) * KH + t / KH) * KH + t % KH];
  bp[i] = f2b(v);
}

// ================= bf16 MFMA GEMM (verified R2): out[N,M] = act(A@W^T + bias) =================
template<bool LEAKY, bool OUTBF>
__global__ __launch_bounds__(256) void mfma_fc(
    const unsigned short* __restrict__ A, const unsigned short* __restrict__ W,
    const float* __restrict__ bias, void* __restrict__ outp, int K, int M) {
  __shared__ unsigned short As[128 * 32];
  __shared__ unsigned short Bs[128 * 32];
  const int tid = threadIdx.x;
  const int wv = tid >> 6, lane = tid & 63;
  const int quad = lane >> 4, l16 = lane & 15;
  const int wr = (wv >> 1) * 64, wc = (wv & 1) * 64;
  const int rb = blockIdx.y * 128, cb = blockIdx.x * 128;

  const int s0 = tid, s1 = tid + 256;
  const int r0 = s0 >> 2, q0 = s0 & 3;
  const int r1 = s1 >> 2, q1 = s1 & 3;
  const unsigned short* A0 = A + (size_t)(rb + r0) * K + q0 * 8;
  const unsigned short* A1 = A + (size_t)(rb + r1) * K + q1 * 8;
  const unsigned short* W0 = W + (size_t)(cb + r0) * K + q0 * 8;
  const unsigned short* W1 = W + (size_t)(cb + r1) * K + q1 * 8;
  void* ldsA0 = (void*)&As[(wv * 64) * 8];
  void* ldsA1 = (void*)&As[(256 + wv * 64) * 8];
  void* ldsB0 = (void*)&Bs[(wv * 64) * 8];
  void* ldsB1 = (void*)&Bs[(256 + wv * 64) * 8];

  f32x4 acc[4][4];
#pragma unroll
  for (int i = 0; i < 4; ++i)
#pragma unroll
    for (int j = 0; j < 4; ++j)
#pragma unroll
      for (int r = 0; r < 4; ++r) acc[i][j][r] = 0.f;

  for (int k0 = 0; k0 < K; k0 += 32) {
    glds16(A0 + k0, ldsA0);
    glds16(A1 + k0, ldsA1);
    glds16(W0 + k0, ldsB0);
    glds16(W1 + k0, ldsB1);
    __syncthreads();
    short8 af[4], bfr[4];
#pragma unroll
    for (int i = 0; i < 4; ++i)
      af[i] = *(const short8*)&As[(wr + i * 16 + l16) * 32 + quad * 8];
#pragma unroll
    for (int j = 0; j < 4; ++j)
      bfr[j] = *(const short8*)&Bs[(wc + j * 16 + l16) * 32 + quad * 8];
#pragma unroll
    for (int i = 0; i < 4; ++i)
#pragma unroll
      for (int j = 0; j < 4; ++j)
        acc[i][j] = __builtin_amdgcn_mfma_f32_16x16x32_bf16(af[i], bfr[j], acc[i][j], 0, 0, 0);
    __syncthreads();
  }

#pragma unroll
  for (int j = 0; j < 4; ++j) {
    const int col = cb + wc + j * 16 + l16;
    const float bj = bias ? bias[col] : 0.f;
#pragma unroll
    for (int i = 0; i < 4; ++i) {
#pragma unroll
      for (int r = 0; r < 4; ++r) {
        const size_t row = rb + wr + i * 16 + quad * 4 + r;
        float v = acc[i][j][r] + bj;
        if (LEAKY) v = v > 0.f ? v : 0.01f * v;
        if (OUTBF) ((unsigned short*)outp)[row * M + col] = f2b(v);
        else       ((float*)outp)[row * M + col] = v;
      }
    }
  }
}

// ============================================================================
// Persistent LSTM v2: 32 blocks x 256 thr, 128 steps, NO cache-maintenance
// fences. Only h crosses blocks: published via device-scope (L2-bypassing)
// relaxed atomic stores, read back as relaxed u64 atomic loads straight into
// MFMA A-fragments (no LDS staging). c lives in registers (block-private
// j-slice). gih[t+1]/done[t+1] prefetched into registers before the flag
// wait, so the post-barrier critical path is h-loads + 128 MFMA + epilogue.
// Handshake: per-block h stores -> s_waitcnt vmcnt(0) -> __syncthreads ->
// one relaxed atomicAdd on a monotonic counter; readers poll relaxed.
// ============================================================================
__global__ __launch_bounds__(256, 1) void lstm_persistent(
    const float* __restrict__ gih_all,       // [T][128][2048] fp32
    const unsigned short* __restrict__ whh,  // bf16 [2048][512]
    unsigned short* h0m,                     // ping (pre-masked bf16), read at even t
    unsigned short* h1m,                     // pong
    const float* __restrict__ cm0,           // fp32 [128][512] pre-masked c0
    const int* __restrict__ done,            // [T][128]
    unsigned short* __restrict__ feat,       // bf16 [T][128][512] unmasked h
    unsigned int* barcnt)
{
  __shared__ unsigned short whs[64][520];
  const int tid = threadIdx.x, wv = tid >> 6, lane = tid & 63;
  const int quad = lane >> 4, l16 = lane & 15;
  const int j0 = blockIdx.x * 16;
  const int j = j0 + l16;

  // preload w_hh slice: row rr -> gate g=rr>>4, j=j0+(rr&15)
  for (int rr = wv; rr < 64; rr += 4) {
    const int g = rr >> 4, jj = rr & 15;
    *(short8*)&whs[rr][lane * 8] =
        *(const short8*)(whh + ((size_t)(g * HID + j0 + jj)) * HID + lane * 8);
  }

  // block-private c slice in registers; cell (i,r) -> b = wv*32+i*16+quad*4+r
  float creg[2][4];
#pragma unroll
  for (int i = 0; i < 2; ++i)
#pragma unroll
    for (int r = 0; r < 4; ++r) {
      const int b = wv * 32 + i * 16 + quad * 4 + r;
      creg[i][r] = cm0[(size_t)b * HID + j];
    }

  // prefetch gih[0] and done[1]
  float gpre[2][4][4];   // [i][r][gate]
  float dnx[2][4];
#pragma unroll
  for (int i = 0; i < 2; ++i)
#pragma unroll
    for (int r = 0; r < 4; ++r) {
      const int b = wv * 32 + i * 16 + quad * 4 + r;
      const float* gp = gih_all + (size_t)b * G4 + j;
#pragma unroll
      for (int g = 0; g < 4; ++g) gpre[i][r][g] = gp[g * HID];
      dnx[i][r] = 1.f - (float)done[BB + b];
    }
  __syncthreads();

  for (int t = 0; t < TT; ++t) {
    const unsigned short* hc = (t & 1) ? h1m : h0m;
    unsigned short* hn = (t & 1) ? h0m : h1m;

    // ---- load all 32 A-frags via device-scope u64 loads (bypass L2) ----
    unsigned long long hb[16][2][2];
#pragma unroll
    for (int kk = 0; kk < 16; ++kk) {
      const unsigned long long* p0 =
          (const unsigned long long*)(hc + (size_t)(wv * 32 + l16) * HID + kk * 32 + quad * 8);
      const unsigned long long* p1 =
          (const unsigned long long*)(hc + (size_t)(wv * 32 + 16 + l16) * HID + kk * 32 + quad * 8);
      hb[kk][0][0] = __hip_atomic_load(p0,     __ATOMIC_RELAXED, __HIP_MEMORY_SCOPE_AGENT);
      hb[kk][0][1] = __hip_atomic_load(p0 + 1, __ATOMIC_RELAXED, __HIP_MEMORY_SCOPE_AGENT);
      hb[kk][1][0] = __hip_atomic_load(p1,     __ATOMIC_RELAXED, __HIP_MEMORY_SCOPE_AGENT);
      hb[kk][1][1] = __hip_atomic_load(p1 + 1, __ATOMIC_RELAXED, __HIP_MEMORY_SCOPE_AGENT);
    }

    f32x4 acc[2][4];
#pragma unroll
    for (int i = 0; i < 2; ++i)
#pragma unroll
      for (int g = 0; g < 4; ++g)
#pragma unroll
        for (int r = 0; r < 4; ++r) acc[i][g][r] = 0.f;

#pragma unroll
    for (int kk = 0; kk < 16; ++kk) {
      union { unsigned long long q[2]; short8 v; } u0, u1;
      u0.q[0] = hb[kk][0][0]; u0.q[1] = hb[kk][0][1];
      u1.q[0] = hb[kk][1][0]; u1.q[1] = hb[kk][1][1];
      short8 b0 = *(const short8*)&whs[l16][kk * 32 + quad * 8];
      short8 b1 = *(const short8*)&whs[16 + l16][kk * 32 + quad * 8];
      short8 b2 = *(const short8*)&whs[32 + l16][kk * 32 + quad * 8];
      short8 b3 = *(const short8*)&whs[48 + l16][kk * 32 + quad * 8];
      acc[0][0] = __builtin_amdgcn_mfma_f32_16x16x32_bf16(u0.v, b0, acc[0][0], 0, 0, 0);
      acc[0][1] = __builtin_amdgcn_mfma_f32_16x16x32_bf16(u0.v, b1, acc[0][1], 0, 0, 0);
      acc[0][2] = __builtin_amdgcn_mfma_f32_16x16x32_bf16(u0.v, b2, acc[0][2], 0, 0, 0);
      acc[0][3] = __builtin_amdgcn_mfma_f32_16x16x32_bf16(u0.v, b3, acc[0][3], 0, 0, 0);
      acc[1][0] = __builtin_amdgcn_mfma_f32_16x16x32_bf16(u1.v, b0, acc[1][0], 0, 0, 0);
      acc[1][1] = __builtin_amdgcn_mfma_f32_16x16x32_bf16(u1.v, b1, acc[1][1], 0, 0, 0);
      acc[1][2] = __builtin_amdgcn_mfma_f32_16x16x32_bf16(u1.v, b2, acc[1][2], 0, 0, 0);
      acc[1][3] = __builtin_amdgcn_mfma_f32_16x16x32_bf16(u1.v, b3, acc[1][3], 0, 0, 0);
    }

    // ---- epilogue: all 4 gates for (b,j) in this lane's accumulators ----
#pragma unroll
    for (int i = 0; i < 2; ++i) {
#pragma unroll
      for (int r = 0; r < 4; ++r) {
        const int b = wv * 32 + i * 16 + quad * 4 + r;
        const float gi = acc[i][0][r] + gpre[i][r][0];
        const float gf = acc[i][1][r] + gpre[i][r][1];
        const float gg = acc[i][2][r] + gpre[i][r][2];
        const float go = acc[i][3][r] + gpre[i][r][3];
        const float i_s = 1.f / (1.f + __expf(-gi));
        const float f_s = 1.f / (1.f + __expf(-gf));
        const float o_s = 1.f / (1.f + __expf(-go));
        const float g_t = tanhf(gg);
        const float c_new = f_s * creg[i][r] + i_s * g_t;
        const float h_new = o_s * tanhf(c_new);
        const float mn = dnx[i][r];
        creg[i][r] = c_new * mn;
        feat[((size_t)t * BB + b) * HID + j] = f2b(h_new);
        if (t < TT - 1) {
          __hip_atomic_store(&hn[(size_t)b * HID + j], f2b(h_new * mn),
                             __ATOMIC_RELAXED, __HIP_MEMORY_SCOPE_AGENT);
        }
      }
    }

    if (t < TT - 1) {
      asm volatile("s_waitcnt vmcnt(0)" ::: "memory");  // h publishes at coherence point
      __syncthreads();                                   // whole block published
      // prefetch next step's gih/done while waiting on other blocks
      const float* gnext = gih_all + (size_t)(t + 1) * BB * G4;
      const int tn2 = (t + 2 < TT) ? t + 2 : TT - 1;
#pragma unroll
      for (int i = 0; i < 2; ++i)
#pragma unroll
        for (int r = 0; r < 4; ++r) {
          const int b = wv * 32 + i * 16 + quad * 4 + r;
          const float* gp = gnext + (size_t)b * G4 + j;
#pragma unroll
          for (int g = 0; g < 4; ++g) gpre[i][r][g] = gp[g * HID];
          dnx[i][r] = 1.f - (float)done[(size_t)tn2 * BB + b];
        }
      if (tid == 0) {
        __hip_atomic_fetch_add(barcnt, 1u, __ATOMIC_RELAXED, __HIP_MEMORY_SCOPE_AGENT);
        const unsigned int target = 32u * (unsigned int)(t + 1);
        while (__hip_atomic_load(barcnt, __ATOMIC_RELAXED, __HIP_MEMORY_SCOPE_AGENT) < target)
          __builtin_amdgcn_s_sleep(2);
      }
      __syncthreads();
    }
  }
}

// ================= small prep kernels =================
__global__ void f2b_kernel(const float* __restrict__ in, unsigned short* __restrict__ out, int n) {
  int i = blockIdx.x * 256 + threadIdx.x;
  if (i < n) out[i] = f2b(in[i]);
}
__global__ void lofpack_kernel(const float* __restrict__ lw, unsigned short* __restrict__ out) {
  int i = blockIdx.x * 256 + threadIdx.x;  // 65536
  int r = i >> 9, c = i & 511;
  out[i] = f2b(lw[r * LOFK + c]);
}
__global__ void bias_add_kernel(const float* __restrict__ a, const float* __restrict__ b,
                                float* __restrict__ o, int n) {
  int i = blockIdx.x * 256 + threadIdx.x;
  if (i < n) o[i] = a[i] + b[i];
}
__global__ void lstm_init_kernel(const float* __restrict__ h0, const float* __restrict__ c0,
                                 const int* __restrict__ done0,
                                 unsigned short* __restrict__ hm, float* __restrict__ cmp) {
  int i = blockIdx.x * 256 + threadIdx.x;  // 65536
  int b = i >> 9;
  float m = 1.f - (float)done0[b];
  hm[i] = f2b(h0[i] * m);
  cmp[i] = c0[i] * m;
}

// ================= heads =================
__global__ __launch_bounds__(256) void heads_kernel(
    const float* __restrict__ raw, const float* __restrict__ lw, const float* __restrict__ lb,
    const float* __restrict__ aw, const float* __restrict__ ab,
    const float* __restrict__ cw, const float* __restrict__ cbias,
    const int* __restrict__ z, const int* __restrict__ action,
    float* __restrict__ out) {
  const int lane = threadIdx.x & 63;
  const int s = blockIdx.x * 4 + (threadIdx.x >> 6);
  const int zv = z[s];
  float v0 = raw[(size_t)s * FE + lane]      + lw[(size_t)lane * LOFK + HID + zv]        + lb[lane];
  float v1 = raw[(size_t)s * FE + 64 + lane] + lw[(size_t)(64 + lane) * LOFK + HID + zv] + lb[64 + lane];
  v0 = v0 > 0.f ? v0 : 0.01f * v0;
  v1 = v1 > 0.f ? v1 : 0.01f * v1;

  float logits[AD];
#pragma unroll
  for (int jj = 0; jj < AD; ++jj) {
    float p = aw[jj * FE + lane] * v0 + aw[jj * FE + 64 + lane] * v1;
#pragma unroll
    for (int o = 32; o > 0; o >>= 1) p += __shfl_down(p, o, 64);
    logits[jj] = __shfl(p, 0, 64) + ab[jj];
  }
  float val = cw[lane] * v0 + cw[64 + lane] * v1;
#pragma unroll
  for (int o = 32; o > 0; o >>= 1) val += __shfl_down(val, o, 64);
  val = __shfl(val, 0, 64) + cbias[0];

  float mx = logits[0];
#pragma unroll
  for (int jj = 1; jj < AD; ++jj) mx = fmaxf(mx, logits[jj]);
  float ex[AD], S = 0.f;
#pragma unroll
  for (int jj = 0; jj < AD; ++jj) { ex[jj] = __expf(logits[jj] - mx); S += ex[jj]; }
  const float inv = 1.f / S;
  const float lZ = __logf(S) + mx;
  float ent = 0.f;
#pragma unroll
  for (int jj = 0; jj < AD; ++jj) ent += (ex[jj] * inv) * (logits[jj] - lZ);
  ent = -ent;
  const float lp_a = logits[action[s]] - lZ;

  if (lane < 10) {
    float v;
    if (lane == 0)      v = lp_a;
    else if (lane == 1) v = ent;
    else if (lane == 2) v = val;
    else                v = ex[lane - 3] * inv;
    out[(size_t)s * 10 + lane] = v;
  }
}

// ================= launch =================
extern "C" void kernel_launch(void* const* d_in, const int* in_sizes, int n_in,
                              void* d_out, int out_size, void* d_ws, size_t ws_size,
                              hipStream_t stream) {
  const float* x       = (const float*)d_in[0];
  const int*   done    = (const int*)d_in[1];
  const int*   z       = (const int*)d_in[2];
  const int*   action  = (const int*)d_in[3];
  const float* h0      = (const float*)d_in[4];
  const float* c0      = (const float*)d_in[5];
  const float* conv1_w = (const float*)d_in[6];
  const float* conv1_b = (const float*)d_in[7];
  const float* conv2_w = (const float*)d_in[8];
  const float* conv2_b = (const float*)d_in[9];
  const float* conv3_w = (const float*)d_in[10];
  const float* conv3_b = (const float*)d_in[11];
  const float* fc1_w   = (const float*)d_in[12];
  const float* fc1_b   = (const float*)d_in[13];
  const float* fc2_w   = (const float*)d_in[14];
  const float* fc2_b   = (const float*)d_in[15];
  const float* w_ih    = (const float*)d_in[16];
  const float* w_hh    = (const float*)d_in[17];
  const float* b_ih    = (const float*)d_in[18];
  const float* b_hh    = (const float*)d_in[19];
  const float* lofeat_w= (const float*)d_in[20];
  const float* lofeat_b= (const float*)d_in[21];
  const float* actor_w = (const float*)d_in[22];
  const float* actor_b = (const float*)d_in[23];
  const float* critic_w= (const float*)d_in[24];
  const float* critic_b= (const float*)d_in[25];
  float* out = (float*)d_out;

  // -------- workspace layout --------
  char* p = (char*)d_ws;
  unsigned short* conv3out = (unsigned short*)p;                 // bf16 TB*4096
  float*          gates    = (float*)p;            p += (size_t)TB * CHW * 2;  // == TB*2048*4 overlay
  unsigned short* fc1out   = (unsigned short*)p;   p += (size_t)TB * HID * 2;
  unsigned short* fc2out   = (unsigned short*)p;   p += (size_t)TB * HID * 2;
  unsigned short* feat     = (unsigned short*)p;   p += (size_t)TB * HID * 2;
  float*          rawlf    = (float*)p;            p += (size_t)TB * FE * 4;
  unsigned short* fc1w_bf  = (unsigned short*)p;   p += (size_t)HID * CHW * 2;
  unsigned short* fc2w_bf  = (unsigned short*)p;   p += (size_t)HID * HID * 2;
  unsigned short* wih_bf   = (unsigned short*)p;   p += (size_t)G4 * HID * 2;
  unsigned short* whh_bf   = (unsigned short*)p;   p += (size_t)G4 * HID * 2;
  unsigned short* lofw_bf  = (unsigned short*)p;   p += (size_t)FE * HID * 2;
  unsigned short* bp1      = (unsigned short*)p;   p += 16 * 416 * 2;
  unsigned short* bp2      = (unsigned short*)p;   p += 16 * 160 * 2;
  unsigned short* bp3      = (unsigned short*)p;   p += 16 * 160 * 2;
  float*          combbias = (float*)p;            p += (size_t)G4 * 4;
  unsigned short* hmA      = (unsigned short*)p;   p += (size_t)BB * HID * 2;
  unsigned short* hmB      = (unsigned short*)p;   p += (size_t)BB * HID * 2;
  float*          cm       = (float*)p;            p += (size_t)BB * HID * 4;
  unsigned int*   barcnt   = (unsigned int*)p;     p += 64;

  // 0. barrier counter must start at 0 (ws is poisoned 0xAA)
  hipMemsetAsync(barcnt, 0, 4, stream);
  // 1. weight packing / conversions
  pack_convw<<<26, 256, 0, stream>>>(conv1_w, bp1, 416, 5);
  pack_convw<<<10, 256, 0, stream>>>(conv2_w, bp2, 160, 3);
  pack_convw<<<10, 256, 0, stream>>>(conv3_w, bp3, 160, 3);
  f2b_kernel<<<(HID * CHW + 255) / 256, 256, 0, stream>>>(fc1_w, fc1w_bf, HID * CHW);
  f2b_kernel<<<(HID * HID + 255) / 256, 256, 0, stream>>>(fc2_w, fc2w_bf, HID * HID);
  f2b_kernel<<<(G4 * HID + 255) / 256, 256, 0, stream>>>(w_ih, wih_bf, G4 * HID);
  f2b_kernel<<<(G4 * HID + 255) / 256, 256, 0, stream>>>(w_hh, whh_bf, G4 * HID);
  lofpack_kernel<<<(FE * HID + 255) / 256, 256, 0, stream>>>(lofeat_w, lofw_bf);
  bias_add_kernel<<<(G4 + 255) / 256, 256, 0, stream>>>(b_ih, b_hh, combbias, G4);
  lstm_init_kernel<<<(BB * HID + 255) / 256, 256, 0, stream>>>(h0, c0, done, hmA, cm);
  // 2. conv stack (MFMA implicit GEMM), bf16 out
  conv_mfma_kernel<<<TB, 256, 0, stream>>>(x, bp1, bp2, bp3,
                                           conv1_b, conv2_b, conv3_b, conv3out);
  // 3. fc1: [TB,4096] x [512,4096]^T -> bf16
  mfma_fc<true, true><<<dim3(HID / 128, TB / 128), 256, 0, stream>>>(
      conv3out, fc1w_bf, fc1_b, fc1out, CHW, HID);
  // 4. fc2
  mfma_fc<true, true><<<dim3(HID / 128, TB / 128), 256, 0, stream>>>(
      fc1out, fc2w_bf, fc2_b, fc2out, HID, HID);
  // 5. gates_ih (+ combined bias) -> fp32, overlays conv3out
  mfma_fc<false, false><<<dim3(G4 / 128, TB / 128), 256, 0, stream>>>(
      fc2out, wih_bf, combbias, gates, HID, G4);
  // 6. LSTM: single persistent kernel, fence-free L3 handshake
  lstm_persistent<<<32, 256, 0, stream>>>(gates, whh_bf, hmA, hmB, cm, done, feat, barcnt);
  // 7. lofeat raw GEMM
  mfma_fc<false, false><<<dim3(FE / 128, TB / 128), 256, 0, stream>>>(
      feat, lofw_bf, nullptr, rawlf, HID, FE);
  // 8. heads
  heads_kernel<<<TB / 4, 256, 0, stream>>>(rawlf, lofeat_w, lofeat_b, actor_w, actor_b,
                                           critic_w, critic_b, z, action, out);
}

// Round 5
// 2272.910 us; speedup vs baseline: 5.2256x; 1.0281x over previous
//
#include <hip/hip_runtime.h>
#include <hip/hip_bf16.h>
#include <math.h>

// ---------------- problem dims ----------------
#define TT   128
#define BB   128
#define TB   (TT*BB)         // 16384
#define CHW  4096
#define HID  512
#define G4   2048            // 4*HID
#define ZD   8
#define AD   7
#define FE   128
#define LOFK 520             // HID + ZD

typedef __attribute__((ext_vector_type(8))) short short8;
typedef __attribute__((ext_vector_type(4))) float f32x4;

__device__ __forceinline__ unsigned short f2b(float f) {
  unsigned int u = __float_as_uint(f);
  unsigned int r = (u + 0x7FFFu + ((u >> 16) & 1u)) >> 16;
  return (unsigned short)r;
}
__device__ __forceinline__ float b2f(unsigned short us) {
  return __uint_as_float(((unsigned int)us) << 16);
}

__device__ __forceinline__ void glds16(const void* g, void* l) {
  __builtin_amdgcn_global_load_lds((const __attribute__((address_space(1))) void*)g,
                                   (__attribute__((address_space(3))) void*)l, 16, 0, 0);
}

// ============================================================================
// Conv as implicit-GEMM MFMA (verified R3). One block per image, 4 waves.
// ============================================================================
__global__ __launch_bounds__(256) void conv_mfma_kernel(
    const float* __restrict__ x,
    const unsigned short* __restrict__ bp1, const unsigned short* __restrict__ bp2,
    const unsigned short* __restrict__ bp3,
    const float* __restrict__ b1, const float* __restrict__ b2, const float* __restrict__ b3,
    unsigned short* __restrict__ out)
{
  __shared__ unsigned short img[2 * 6400];   // two 20*20*16 bf16 buffers
  const int tid = threadIdx.x;
  const int wv = tid >> 6, lane = tid & 63, quad = lane >> 4, l16 = lane & 15;
  const int imgid = blockIdx.x;
  unsigned short* buf0 = img;
  unsigned short* buf1 = img + 6400;

  {
    int4 z = {0, 0, 0, 0};
    for (int i = tid; i < 1600; i += 256) ((int4*)img)[i] = z;
  }
  __syncthreads();
  const float* src = x + (size_t)imgid * CHW;
  for (int i = tid; i < CHW; i += 256) {
    const int ci = i >> 8, rem = i & 255, y = rem >> 4, xx = rem & 15;
    buf0[(((ci >> 3) * 400) + (y + 2) * 20 + (xx + 2)) * 8 + (ci & 7)] = f2b(src[i]);
  }
  __syncthreads();

  // ---- stage 1: 5x5, K=416 ----
  {
    short8 bf[13];
#pragma unroll
    for (int s = 0; s < 13; ++s)
      bf[s] = *(const short8*)(bp1 + l16 * 416 + s * 32 + quad * 8);
    f32x4 acc[4];
#pragma unroll
    for (int mt = 0; mt < 4; ++mt)
#pragma unroll
      for (int r = 0; r < 4; ++r) acc[mt][r] = 0.f;
#pragma unroll
    for (int s = 0; s < 13; ++s) {
      int t = 2 * s + (quad >> 1); if (t > 24) t = 24;
      const int ky = t / 5, kx = t - ky * 5;
      const int base = ((quad & 1) * 400 + ky * 20 + l16 + kx) * 8;
#pragma unroll
      for (int mt = 0; mt < 4; ++mt) {
        const int y = wv * 4 + mt;
        short8 a = *(const short8*)&buf0[base + y * 160];
        acc[mt] = __builtin_amdgcn_mfma_f32_16x16x32_bf16(a, bf[s], acc[mt], 0, 0, 0);
      }
    }
    const float bias = b1[l16];
#pragma unroll
    for (int mt = 0; mt < 4; ++mt) {
      const int y = wv * 4 + mt;
#pragma unroll
      for (int r = 0; r < 4; ++r) {
        float v = acc[mt][r] + bias;
        v = v > 0.f ? v : 0.01f * v;
        const int xx = quad * 4 + r;
        buf1[(((l16 >> 3) * 400) + (y + 2) * 20 + (xx + 2)) * 8 + (l16 & 7)] = f2b(v);
      }
    }
  }
  __syncthreads();

  // ---- stage 2: 3x3, K=160 ----
  {
    short8 bf[5];
#pragma unroll
    for (int s = 0; s < 5; ++s)
      bf[s] = *(const short8*)(bp2 + l16 * 160 + s * 32 + quad * 8);
    f32x4 acc[4];
#pragma unroll
    for (int mt = 0; mt < 4; ++mt)
#pragma unroll
      for (int r = 0; r < 4; ++r) acc[mt][r] = 0.f;
#pragma unroll
    for (int s = 0; s < 5; ++s) {
      int t = 2 * s + (quad >> 1); if (t > 8) t = 8;
      const int ky = t / 3, kx = t - ky * 3;
      const int base = ((quad & 1) * 400 + (ky + 1) * 20 + l16 + kx + 1) * 8;
#pragma unroll
      for (int mt = 0; mt < 4; ++mt) {
        const int y = wv * 4 + mt;
        short8 a = *(const short8*)&buf1[base + y * 160];
        acc[mt] = __builtin_amdgcn_mfma_f32_16x16x32_bf16(a, bf[s], acc[mt], 0, 0, 0);
      }
    }
    const float bias = b2[l16];
#pragma unroll
    for (int mt = 0; mt < 4; ++mt) {
      const int y = wv * 4 + mt;
#pragma unroll
      for (int r = 0; r < 4; ++r) {
        float v = acc[mt][r] + bias;
        v = v > 0.f ? v : 0.01f * v;
        const int xx = quad * 4 + r;
        buf0[(((l16 >> 3) * 400) + (y + 2) * 20 + (xx + 2)) * 8 + (l16 & 7)] = f2b(v);
      }
    }
  }
  __syncthreads();

  // ---- stage 3: 3x3 -> global bf16 NCHW ----
  {
    short8 bf[5];
#pragma unroll
    for (int s = 0; s < 5; ++s)
      bf[s] = *(const short8*)(bp3 + l16 * 160 + s * 32 + quad * 8);
    f32x4 acc[4];
#pragma unroll
    for (int mt = 0; mt < 4; ++mt)
#pragma unroll
      for (int r = 0; r < 4; ++r) acc[mt][r] = 0.f;
#pragma unroll
    for (int s = 0; s < 5; ++s) {
      int t = 2 * s + (quad >> 1); if (t > 8) t = 8;
      const int ky = t / 3, kx = t - ky * 3;
      const int base = ((quad & 1) * 400 + (ky + 1) * 20 + l16 + kx + 1) * 8;
#pragma unroll
      for (int mt = 0; mt < 4; ++mt) {
        const int y = wv * 4 + mt;
        short8 a = *(const short8*)&buf0[base + y * 160];
        acc[mt] = __builtin_amdgcn_mfma_f32_16x16x32_bf16(a, bf[s], acc[mt], 0, 0, 0);
      }
    }
    const float bias = b3[l16];
    unsigned short* dst = out + (size_t)imgid * CHW;
#pragma unroll
    for (int mt = 0; mt < 4; ++mt) {
      const int y = wv * 4 + mt;
      ushort4 pk;
      float v;
      v = acc[mt][0] + bias; v = v > 0.f ? v : 0.01f * v; pk.x = f2b(v);
      v = acc[mt][1] + bias; v = v > 0.f ? v : 0.01f * v; pk.y = f2b(v);
      v = acc[mt][2] + bias; v = v > 0.f ? v : 0.01f * v; pk.z = f2b(v);
      v = acc[mt][3] + bias; v = v > 0.f ? v : 0.01f * v; pk.w = f2b(v);
      *(ushort4*)(dst + l16 * 256 + y * 16 + quad * 4) = pk;
    }
  }
}

// pack conv weights OIHW fp32 -> Bp[co][k] bf16, k = tap*16+ci, K mult of 32
__global__ void pack_convw(const float* __restrict__ w, unsigned short* __restrict__ bp,
                           int K, int KH) {
  int i = blockIdx.x * 256 + threadIdx.x;
  if (i >= 16 * K) return;
  int co = i / K, k = i - co * K;
  int t = k >> 4, ci = k & 15;
  float v = 0.f;
  if (t < KH * KH) v = w[((co * 16 + ci) * KH + t / KH) * KH + t % KH];
  bp[i] = f2b(v);
}

// ================= bf16 MFMA GEMM: out[N,M] = act(A@W^T + bias) =================
// MODE: 0 = fp32 out, 1 = bf16 out, 2 = gate-packed bf16 out (row*M + (col&511)*4 + (col>>9))
template<bool LEAKY, int MODE>
__global__ __launch_bounds__(256) void mfma_fc(
    const unsigned short* __restrict__ A, const unsigned short* __restrict__ W,
    const float* __restrict__ bias, void* __restrict__ outp, int K, int M) {
  __shared__ unsigned short As[128 * 32];
  __shared__ unsigned short Bs[128 * 32];
  const int tid = threadIdx.x;
  const int wv = tid >> 6, lane = tid & 63;
  const int quad = lane >> 4, l16 = lane & 15;
  const int wr = (wv >> 1) * 64, wc = (wv & 1) * 64;
  const int rb = blockIdx.y * 128, cb = blockIdx.x * 128;

  const int s0 = tid, s1 = tid + 256;
  const int r0 = s0 >> 2, q0 = s0 & 3;
  const int r1 = s1 >> 2, q1 = s1 & 3;
  const unsigned short* A0 = A + (size_t)(rb + r0) * K + q0 * 8;
  const unsigned short* A1 = A + (size_t)(rb + r1) * K + q1 * 8;
  const unsigned short* W0 = W + (size_t)(cb + r0) * K + q0 * 8;
  const unsigned short* W1 = W + (size_t)(cb + r1) * K + q1 * 8;
  void* ldsA0 = (void*)&As[(wv * 64) * 8];
  void* ldsA1 = (void*)&As[(256 + wv * 64) * 8];
  void* ldsB0 = (void*)&Bs[(wv * 64) * 8];
  void* ldsB1 = (void*)&Bs[(256 + wv * 64) * 8];

  f32x4 acc[4][4];
#pragma unroll
  for (int i = 0; i < 4; ++i)
#pragma unroll
    for (int j = 0; j < 4; ++j)
#pragma unroll
      for (int r = 0; r < 4; ++r) acc[i][j][r] = 0.f;

  for (int k0 = 0; k0 < K; k0 += 32) {
    glds16(A0 + k0, ldsA0);
    glds16(A1 + k0, ldsA1);
    glds16(W0 + k0, ldsB0);
    glds16(W1 + k0, ldsB1);
    __syncthreads();
    short8 af[4], bfr[4];
#pragma unroll
    for (int i = 0; i < 4; ++i)
      af[i] = *(const short8*)&As[(wr + i * 16 + l16) * 32 + quad * 8];
#pragma unroll
    for (int j = 0; j < 4; ++j)
      bfr[j] = *(const short8*)&Bs[(wc + j * 16 + l16) * 32 + quad * 8];
#pragma unroll
    for (int i = 0; i < 4; ++i)
#pragma unroll
      for (int j = 0; j < 4; ++j)
        acc[i][j] = __builtin_amdgcn_mfma_f32_16x16x32_bf16(af[i], bfr[j], acc[i][j], 0, 0, 0);
    __syncthreads();
  }

#pragma unroll
  for (int j = 0; j < 4; ++j) {
    const int col = cb + wc + j * 16 + l16;
    const float bj = bias ? bias[col] : 0.f;
#pragma unroll
    for (int i = 0; i < 4; ++i) {
#pragma unroll
      for (int r = 0; r < 4; ++r) {
        const size_t row = rb + wr + i * 16 + quad * 4 + r;
        float v = acc[i][j][r] + bj;
        if (LEAKY) v = v > 0.f ? v : 0.01f * v;
        if (MODE == 0)      ((float*)outp)[row * M + col] = v;
        else if (MODE == 1) ((unsigned short*)outp)[row * M + col] = f2b(v);
        else {
          const size_t idx = row * M + ((size_t)(col & (HID - 1)) * 4 + (col >> 9));
          ((unsigned short*)outp)[idx] = f2b(v);
        }
      }
    }
  }
}

// ============================================================================
// Persistent LSTM v3: 32 blocks x 256 thr. Per step:
//  - parallel poll of all 32 per-block flags (lane l polls flag l, 256B lines)
//  - prefetch packed-bf16 gih(t+1) (8 u64/thread) + done(t+2)
//  - 16 unrolled k-chunks: 4 u64 L2-bypass h loads + 4 ds_read_b128 + 8 MFMA
//  - register epilogue (c in regs), publish h/feat via LDS-coalesced u64 stores
//  - s_waitcnt vmcnt(0) -> __syncthreads -> tid0 bumps own flag
// ============================================================================
__global__ __launch_bounds__(256, 1) void lstm_persistent(
    const unsigned short* __restrict__ gpk,   // bf16 [T][B][HID][4] packed gates_ih
    const unsigned short* __restrict__ whh,   // bf16 [2048][512]
    unsigned short* h0m, unsigned short* h1m, // ping/pong pre-masked h (bf16)
    const float* __restrict__ cm0,            // fp32 [128][512] pre-masked c0
    const int* __restrict__ done,             // [T][128]
    unsigned short* __restrict__ feat,        // bf16 [T][128][512] unmasked h
    unsigned int* flags)                      // [32] monotonic, stride 64 ints
{
  __shared__ unsigned short whs[64][520];
  __shared__ unsigned short hpub[128][16];
  __shared__ unsigned short fpub[128][16];
  const int tid = threadIdx.x, wv = tid >> 6, lane = tid & 63;
  const int quad = lane >> 4, l16 = lane & 15;
  const int bid = blockIdx.x;
  const int j0 = bid * 16;
  const int j = j0 + l16;

  // preload w_hh slice: row rr -> gate g=rr>>4, col j0+(rr&15)
  for (int rr = wv; rr < 64; rr += 4)
    *(short8*)&whs[rr][lane * 8] =
        *(const short8*)(whh + ((size_t)((rr >> 4) * HID + j0 + (rr & 15))) * HID + lane * 8);

  // per-thread cells (i in 2, r in 4): b = wv*32 + i*16 + quad*4 + r, col j
  float creg[2][4], dcur[2][4];
  unsigned long long gcur[2][4], gnxt[2][4];
  int dnxt[2][4];
#pragma unroll
  for (int i = 0; i < 2; ++i)
#pragma unroll
    for (int r = 0; r < 4; ++r) {
      const int b = wv * 32 + i * 16 + quad * 4 + r;
      creg[i][r] = cm0[(size_t)b * HID + j];
      gcur[i][r] = *(const unsigned long long*)(gpk + ((size_t)b * HID + j) * 4);
      dcur[i][r] = 1.f - (float)done[BB + b];
    }
  __syncthreads();

  for (int t = 0; t < TT; ++t) {
    const unsigned short* hc = (t & 1) ? h1m : h0m;
    unsigned short* hn = (t & 1) ? h0m : h1m;

    // ---- wait for all 32 producers of h(t) (parallel poll) ----
    if (t > 0) {
      const unsigned int need = (unsigned int)t;
      for (;;) {
        unsigned int v = 0xffffffffu;
        if (lane < 32)
          v = __hip_atomic_load(&flags[lane << 6], __ATOMIC_RELAXED, __HIP_MEMORY_SCOPE_AGENT);
        unsigned long long ok = __ballot(v >= need);
        if (ok == ~0ull) break;
        __builtin_amdgcn_s_sleep(1);
      }
    }

    // ---- prefetch next step's gih/done (latency hidden under MFMA chunks) ----
    if (t + 1 < TT) {
      const unsigned short* gn = gpk + (size_t)(t + 1) * BB * HID * 4;
      const int tn2 = (t + 2 < TT) ? t + 2 : TT - 1;
#pragma unroll
      for (int i = 0; i < 2; ++i)
#pragma unroll
        for (int r = 0; r < 4; ++r) {
          const int b = wv * 32 + i * 16 + quad * 4 + r;
          gnxt[i][r] = *(const unsigned long long*)(gn + ((size_t)b * HID + j) * 4);
          dnxt[i][r] = done[(size_t)tn2 * BB + b];
        }
    }

    f32x4 acc[2][4];
#pragma unroll
    for (int i = 0; i < 2; ++i)
#pragma unroll
      for (int g = 0; g < 4; ++g)
#pragma unroll
        for (int r = 0; r < 4; ++r) acc[i][g][r] = 0.f;

    // ---- 16 k-chunks, fully unrolled ----
#pragma unroll
    for (int ci = 0; ci < 16; ++ci) {
      const int m = (ci + (bid >> 1) + 1) & 15;
      const int k = m * 32 + quad * 8;
      const unsigned long long* pa0 =
          (const unsigned long long*)(hc + (size_t)(wv * 32 + l16) * HID + k);
      const unsigned long long* pa1 =
          (const unsigned long long*)(hc + (size_t)(wv * 32 + 16 + l16) * HID + k);
      union { unsigned long long q[2]; short8 v; } a0, a1;
      a0.q[0] = __hip_atomic_load(pa0,     __ATOMIC_RELAXED, __HIP_MEMORY_SCOPE_AGENT);
      a0.q[1] = __hip_atomic_load(pa0 + 1, __ATOMIC_RELAXED, __HIP_MEMORY_SCOPE_AGENT);
      a1.q[0] = __hip_atomic_load(pa1,     __ATOMIC_RELAXED, __HIP_MEMORY_SCOPE_AGENT);
      a1.q[1] = __hip_atomic_load(pa1 + 1, __ATOMIC_RELAXED, __HIP_MEMORY_SCOPE_AGENT);
      short8 b0 = *(const short8*)&whs[l16][k];
      short8 b1 = *(const short8*)&whs[16 + l16][k];
      short8 b2 = *(const short8*)&whs[32 + l16][k];
      short8 b3 = *(const short8*)&whs[48 + l16][k];
      acc[0][0] = __builtin_amdgcn_mfma_f32_16x16x32_bf16(a0.v, b0, acc[0][0], 0, 0, 0);
      acc[0][1] = __builtin_amdgcn_mfma_f32_16x16x32_bf16(a0.v, b1, acc[0][1], 0, 0, 0);
      acc[0][2] = __builtin_amdgcn_mfma_f32_16x16x32_bf16(a0.v, b2, acc[0][2], 0, 0, 0);
      acc[0][3] = __builtin_amdgcn_mfma_f32_16x16x32_bf16(a0.v, b3, acc[0][3], 0, 0, 0);
      acc[1][0] = __builtin_amdgcn_mfma_f32_16x16x32_bf16(a1.v, b0, acc[1][0], 0, 0, 0);
      acc[1][1] = __builtin_amdgcn_mfma_f32_16x16x32_bf16(a1.v, b1, acc[1][1], 0, 0, 0);
      acc[1][2] = __builtin_amdgcn_mfma_f32_16x16x32_bf16(a1.v, b2, acc[1][2], 0, 0, 0);
      acc[1][3] = __builtin_amdgcn_mfma_f32_16x16x32_bf16(a1.v, b3, acc[1][3], 0, 0, 0);
    }

    // ---- cell epilogue (register-only state), write LDS pub buffers ----
#pragma unroll
    for (int i = 0; i < 2; ++i) {
#pragma unroll
      for (int r = 0; r < 4; ++r) {
        const int b = wv * 32 + i * 16 + quad * 4 + r;
        const unsigned long long gq = gcur[i][r];
        const float gi = acc[i][0][r] + b2f((unsigned short)gq);
        const float gf = acc[i][1][r] + b2f((unsigned short)(gq >> 16));
        const float gg = acc[i][2][r] + b2f((unsigned short)(gq >> 32));
        const float go = acc[i][3][r] + b2f((unsigned short)(gq >> 48));
        const float i_s = 1.f / (1.f + __expf(-gi));
        const float f_s = 1.f / (1.f + __expf(-gf));
        const float o_s = 1.f / (1.f + __expf(-go));
        const float g_t = tanhf(gg);
        const float c_new = f_s * creg[i][r] + i_s * g_t;
        const float h_new = o_s * tanhf(c_new);
        const float mn = dcur[i][r];
        creg[i][r] = c_new * mn;
        hpub[b][l16] = f2b(h_new * mn);
        fpub[b][l16] = f2b(h_new);
      }
    }
    __syncthreads();

    // ---- coalesced publish: 2 u64 feat + 2 u64 h per thread ----
    {
      const int q0 = tid, q1 = tid + 256;
      const unsigned long long fv0 = *(const unsigned long long*)&fpub[q0 >> 2][(q0 & 3) * 4];
      const unsigned long long fv1 = *(const unsigned long long*)&fpub[q1 >> 2][(q1 & 3) * 4];
      *(unsigned long long*)(feat + ((size_t)t * BB + (q0 >> 2)) * HID + j0 + (q0 & 3) * 4) = fv0;
      *(unsigned long long*)(feat + ((size_t)t * BB + (q1 >> 2)) * HID + j0 + (q1 & 3) * 4) = fv1;
      if (t < TT - 1) {
        const unsigned long long hv0 = *(const unsigned long long*)&hpub[q0 >> 2][(q0 & 3) * 4];
        const unsigned long long hv1 = *(const unsigned long long*)&hpub[q1 >> 2][(q1 & 3) * 4];
        __hip_atomic_store((unsigned long long*)(hn + (size_t)(q0 >> 2) * HID + j0 + (q0 & 3) * 4),
                           hv0, __ATOMIC_RELAXED, __HIP_MEMORY_SCOPE_AGENT);
        __hip_atomic_store((unsigned long long*)(hn + (size_t)(q1 >> 2) * HID + j0 + (q1 & 3) * 4),
                           hv1, __ATOMIC_RELAXED, __HIP_MEMORY_SCOPE_AGENT);
      }
      asm volatile("s_waitcnt vmcnt(0)" ::: "memory");
    }
    __syncthreads();   // whole block's h published; also protects hpub reuse
    if (t < TT - 1 && tid == 0)
      __hip_atomic_fetch_add(&flags[bid << 6], 1u, __ATOMIC_RELAXED, __HIP_MEMORY_SCOPE_AGENT);

#pragma unroll
    for (int i = 0; i < 2; ++i)
#pragma unroll
      for (int r = 0; r < 4; ++r) {
        gcur[i][r] = gnxt[i][r];
        dcur[i][r] = 1.f - (float)dnxt[i][r];
      }
  }
}

// ================= small prep kernels =================
__global__ void f2b_kernel(const float* __restrict__ in, unsigned short* __restrict__ out, int n) {
  int i = blockIdx.x * 256 + threadIdx.x;
  if (i < n) out[i] = f2b(in[i]);
}
__global__ void lofpack_kernel(const float* __restrict__ lw, unsigned short* __restrict__ out) {
  int i = blockIdx.x * 256 + threadIdx.x;  // 65536
  int r = i >> 9, c = i & 511;
  out[i] = f2b(lw[r * LOFK + c]);
}
__global__ void bias_add_kernel(const float* __restrict__ a, const float* __restrict__ b,
                                float* __restrict__ o, int n) {
  int i = blockIdx.x * 256 + threadIdx.x;
  if (i < n) o[i] = a[i] + b[i];
}
__global__ void lstm_init_kernel(const float* __restrict__ h0, const float* __restrict__ c0,
                                 const int* __restrict__ done0,
                                 unsigned short* __restrict__ hm, float* __restrict__ cmp) {
  int i = blockIdx.x * 256 + threadIdx.x;  // 65536
  int b = i >> 9;
  float m = 1.f - (float)done0[b];
  hm[i] = f2b(h0[i] * m);
  cmp[i] = c0[i] * m;
}

// ================= heads =================
__global__ __launch_bounds__(256) void heads_kernel(
    const float* __restrict__ raw, const float* __restrict__ lw, const float* __restrict__ lb,
    const float* __restrict__ aw, const float* __restrict__ ab,
    const float* __restrict__ cw, const float* __restrict__ cbias,
    const int* __restrict__ z, const int* __restrict__ action,
    float* __restrict__ out) {
  const int lane = threadIdx.x & 63;
  const int s = blockIdx.x * 4 + (threadIdx.x >> 6);
  const int zv = z[s];
  float v0 = raw[(size_t)s * FE + lane]      + lw[(size_t)lane * LOFK + HID + zv]        + lb[lane];
  float v1 = raw[(size_t)s * FE + 64 + lane] + lw[(size_t)(64 + lane) * LOFK + HID + zv] + lb[64 + lane];
  v0 = v0 > 0.f ? v0 : 0.01f * v0;
  v1 = v1 > 0.f ? v1 : 0.01f * v1;

  float logits[AD];
#pragma unroll
  for (int jj = 0; jj < AD; ++jj) {
    float p = aw[jj * FE + lane] * v0 + aw[jj * FE + 64 + lane] * v1;
#pragma unroll
    for (int o = 32; o > 0; o >>= 1) p += __shfl_down(p, o, 64);
    logits[jj] = __shfl(p, 0, 64) + ab[jj];
  }
  float val = cw[lane] * v0 + cw[64 + lane] * v1;
#pragma unroll
  for (int o = 32; o > 0; o >>= 1) val += __shfl_down(val, o, 64);
  val = __shfl(val, 0, 64) + cbias[0];

  float mx = logits[0];
#pragma unroll
  for (int jj = 1; jj < AD; ++jj) mx = fmaxf(mx, logits[jj]);
  float ex[AD], S = 0.f;
#pragma unroll
  for (int jj = 0; jj < AD; ++jj) { ex[jj] = __expf(logits[jj] - mx); S += ex[jj]; }
  const float inv = 1.f / S;
  const float lZ = __logf(S) + mx;
  float ent = 0.f;
#pragma unroll
  for (int jj = 0; jj < AD; ++jj) ent += (ex[jj] * inv) * (logits[jj] - lZ);
  ent = -ent;
  const float lp_a = logits[action[s]] - lZ;

  if (lane < 10) {
    float v;
    if (lane == 0)      v = lp_a;
    else if (lane == 1) v = ent;
    else if (lane == 2) v = val;
    else                v = ex[lane - 3] * inv;
    out[(size_t)s * 10 + lane] = v;
  }
}

// ================= launch =================
extern "C" void kernel_launch(void* const* d_in, const int* in_sizes, int n_in,
                              void* d_out, int out_size, void* d_ws, size_t ws_size,
                              hipStream_t stream) {
  const float* x       = (const float*)d_in[0];
  const int*   done    = (const int*)d_in[1];
  const int*   z       = (const int*)d_in[2];
  const int*   action  = (const int*)d_in[3];
  const float* h0      = (const float*)d_in[4];
  const float* c0      = (const float*)d_in[5];
  const float* conv1_w = (const float*)d_in[6];
  const float* conv1_b = (const float*)d_in[7];
  const float* conv2_w = (const float*)d_in[8];
  const float* conv2_b = (const float*)d_in[9];
  const float* conv3_w = (const float*)d_in[10];
  const float* conv3_b = (const float*)d_in[11];
  const float* fc1_w   = (const float*)d_in[12];
  const float* fc1_b   = (const float*)d_in[13];
  const float* fc2_w   = (const float*)d_in[14];
  const float* fc2_b   = (const float*)d_in[15];
  const float* w_ih    = (const float*)d_in[16];
  const float* w_hh    = (const float*)d_in[17];
  const float* b_ih    = (const float*)d_in[18];
  const float* b_hh    = (const float*)d_in[19];
  const float* lofeat_w= (const float*)d_in[20];
  const float* lofeat_b= (const float*)d_in[21];
  const float* actor_w = (const float*)d_in[22];
  const float* actor_b = (const float*)d_in[23];
  const float* critic_w= (const float*)d_in[24];
  const float* critic_b= (const float*)d_in[25];
  float* out = (float*)d_out;

  // -------- workspace layout --------
  char* p = (char*)d_ws;
  unsigned short* conv3out = (unsigned short*)p;                 // bf16 TB*4096
  unsigned short* gatesP   = (unsigned short*)p;                 // overlay: bf16 TB*2048 packed
  p += (size_t)TB * CHW * 2;
  unsigned short* fc1out   = (unsigned short*)p;   p += (size_t)TB * HID * 2;
  unsigned short* fc2out   = (unsigned short*)p;   p += (size_t)TB * HID * 2;
  unsigned short* feat     = (unsigned short*)p;   p += (size_t)TB * HID * 2;
  float*          rawlf    = (float*)p;            p += (size_t)TB * FE * 4;
  unsigned short* fc1w_bf  = (unsigned short*)p;   p += (size_t)HID * CHW * 2;
  unsigned short* fc2w_bf  = (unsigned short*)p;   p += (size_t)HID * HID * 2;
  unsigned short* wih_bf   = (unsigned short*)p;   p += (size_t)G4 * HID * 2;
  unsigned short* whh_bf   = (unsigned short*)p;   p += (size_t)G4 * HID * 2;
  unsigned short* lofw_bf  = (unsigned short*)p;   p += (size_t)FE * HID * 2;
  unsigned short* bp1      = (unsigned short*)p;   p += 16 * 416 * 2;
  unsigned short* bp2      = (unsigned short*)p;   p += 16 * 160 * 2;
  unsigned short* bp3      = (unsigned short*)p;   p += 16 * 160 * 2;
  float*          combbias = (float*)p;            p += (size_t)G4 * 4;
  unsigned short* hmA      = (unsigned short*)p;   p += (size_t)BB * HID * 2;
  unsigned short* hmB      = (unsigned short*)p;   p += (size_t)BB * HID * 2;
  float*          cm       = (float*)p;            p += (size_t)BB * HID * 4;
  unsigned int*   flags    = (unsigned int*)p;     p += 32 * 64 * 4;

  // 0. flags must start at 0 (ws is poisoned 0xAA)
  hipMemsetAsync(flags, 0, 32 * 64 * 4, stream);
  // 1. weight packing / conversions
  pack_convw<<<26, 256, 0, stream>>>(conv1_w, bp1, 416, 5);
  pack_convw<<<10, 256, 0, stream>>>(conv2_w, bp2, 160, 3);
  pack_convw<<<10, 256, 0, stream>>>(conv3_w, bp3, 160, 3);
  f2b_kernel<<<(HID * CHW + 255) / 256, 256, 0, stream>>>(fc1_w, fc1w_bf, HID * CHW);
  f2b_kernel<<<(HID * HID + 255) / 256, 256, 0, stream>>>(fc2_w, fc2w_bf, HID * HID);
  f2b_kernel<<<(G4 * HID + 255) / 256, 256, 0, stream>>>(w_ih, wih_bf, G4 * HID);
  f2b_kernel<<<(G4 * HID + 255) / 256, 256, 0, stream>>>(w_hh, whh_bf, G4 * HID);
  lofpack_kernel<<<(FE * HID + 255) / 256, 256, 0, stream>>>(lofeat_w, lofw_bf);
  bias_add_kernel<<<(G4 + 255) / 256, 256, 0, stream>>>(b_ih, b_hh, combbias, G4);
  lstm_init_kernel<<<(BB * HID + 255) / 256, 256, 0, stream>>>(h0, c0, done, hmA, cm);
  // 2. conv stack (MFMA implicit GEMM), bf16 out
  conv_mfma_kernel<<<TB, 256, 0, stream>>>(x, bp1, bp2, bp3,
                                           conv1_b, conv2_b, conv3_b, conv3out);
  // 3. fc1: [TB,4096] x [512,4096]^T -> bf16
  mfma_fc<true, 1><<<dim3(HID / 128, TB / 128), 256, 0, stream>>>(
      conv3out, fc1w_bf, fc1_b, fc1out, CHW, HID);
  // 4. fc2
  mfma_fc<true, 1><<<dim3(HID / 128, TB / 128), 256, 0, stream>>>(
      fc1out, fc2w_bf, fc2_b, fc2out, HID, HID);
  // 5. gates_ih (+ combined bias) -> packed bf16 [t][b][j][gate], overlays conv3out
  mfma_fc<false, 2><<<dim3(G4 / 128, TB / 128), 256, 0, stream>>>(
      fc2out, wih_bf, combbias, gatesP, HID, G4);
  // 6. LSTM: single persistent kernel, parallel-flag handshake
  lstm_persistent<<<32, 256, 0, stream>>>(gatesP, whh_bf, hmA, hmB, cm, done, feat, flags);
  // 7. lofeat raw GEMM
  mfma_fc<false, 0><<<dim3(FE / 128, TB / 128), 256, 0, stream>>>(
      feat, lofw_bf, nullptr, rawlf, HID, FE);
  // 8. heads
  heads_kernel<<<TB / 4, 256, 0, stream>>>(rawlf, lofeat_w, lofeat_b, actor_w, actor_b,
                                           critic_w, critic_b, z, action, out);
}